// Round 1
// baseline (13651.855 us; speedup 1.0000x reference)
//
#include <hip/hip_runtime.h>
#include <math.h>

#define HWN 4096
#define Bn 4
#define Tn 8
#define HC 64
#define S_ELEMS (Bn*HC*HWN)   // 1048576 elems = 4 MB

__device__ __forceinline__ float sigmoidf_(float v) { return 1.f / (1.f + expf(-v)); }

// ---------------------------------------------------------------------------
// Generic 3x3 SAME conv, input = concat([in1 (C1 ch), in2 (C2 ch)]).
// Block: 256 thr, 32x32 spatial tile, Q output channels.
// grid.x = 4 spatial tiles, grid.y = Cout/Q, grid.z = B (or 2B for dual mode:
// second half uses in2b/outb — used to fuse the gc and gm convs).
// ---------------------------------------------------------------------------
template<int Q, int TANH>
__global__ __launch_bounds__(256) void conv3_kernel(
    const float* __restrict__ in1, int C1, int sb1,
    const float* __restrict__ in2a, const float* __restrict__ in2b, int C2, int sb2,
    const float* __restrict__ wt, const float* __restrict__ bias,
    float* __restrict__ outa, float* __restrict__ outb, int Cout)
{
    const int NCH = 4;
    __shared__ __align__(16) float slds[NCH][34 * 34];
    __shared__ __align__(16) float wlds[NCH][9][Q];

    const int tid  = threadIdx.x;
    const int tile = blockIdx.x;
    const int co0  = blockIdx.y * Q;
    const int bz   = blockIdx.z;
    const int b     = bz & 3;
    const int which = bz >> 2;
    const float* in2 = which ? in2b : in2a;
    float*       out = which ? outb : outa;

    const int ty0 = (tile >> 1) * 32;
    const int tx0 = (tile & 1) * 32;
    const int col  = tid & 31;
    const int row0 = tid >> 5;   // 0..7 ; pixels at rows row0+{0,8,16,24}

    const int Ctot = C1 + C2;
    float acc[4][Q];
#pragma unroll
    for (int p = 0; p < 4; ++p)
#pragma unroll
        for (int q = 0; q < Q; ++q) acc[p][q] = 0.f;

    const float* in1b = in1 + (long)b * sb1;
    const float* in2bp = in2 + (long)b * sb2;

    for (int c0 = 0; c0 < Ctot; c0 += NCH) {
        __syncthreads();
        // stage 4 input channels, 34x34 halo tile each
        for (int i = tid; i < NCH * 34 * 34; i += 256) {
            int cc  = i / (34 * 34);
            int rem = i - cc * (34 * 34);
            int r    = rem / 34;
            int cpos = rem - r * 34;
            int y = ty0 - 1 + r;
            int x = tx0 - 1 + cpos;
            float v = 0.f;
            if ((unsigned)y < 64u && (unsigned)x < 64u) {
                int ch = c0 + cc;
                const float* src = (ch < C1) ? (in1b + (long)ch * HWN)
                                             : (in2bp + (long)(ch - C1) * HWN);
                v = src[y * 64 + x];
            }
            slds[cc][rem] = v;
        }
        // stage weights: wlds[cc][k][q] (cout contiguous -> b128 reads)
        for (int i = tid; i < NCH * 9 * Q; i += 256) {
            int cc  = i / (9 * Q);
            int rem = i - cc * (9 * Q);
            int k = rem / Q;
            int q = rem - k * Q;
            wlds[cc][k][q] = wt[((long)(co0 + q) * Ctot + (c0 + cc)) * 9 + k];
        }
        __syncthreads();

#pragma unroll
        for (int cc = 0; cc < NCH; ++cc) {
#pragma unroll
            for (int k = 0; k < 9; ++k) {
                const int ky = k / 3, kx = k - ky * 3;
                float wv[Q];
#pragma unroll
                for (int q4 = 0; q4 < Q / 4; ++q4)
                    *(float4*)&wv[q4 * 4] = *(const float4*)&wlds[cc][k][q4 * 4];
#pragma unroll
                for (int p = 0; p < 4; ++p) {
                    float xv = slds[cc][(row0 + p * 8 + ky) * 34 + (col + kx)];
#pragma unroll
                    for (int q = 0; q < Q; ++q)
                        acc[p][q] = fmaf(xv, wv[q], acc[p][q]);
                }
            }
        }
    }

    const long outbB = (long)b * Cout * HWN;
#pragma unroll
    for (int q = 0; q < Q; ++q) {
        float bq = bias[co0 + q];
#pragma unroll
        for (int p = 0; p < 4; ++p) {
            float v = acc[p][q] + bq;
            if (TANH) v = tanhf(v);
            out[outbB + (long)(co0 + q) * HWN + (ty0 + row0 + p * 8) * 64 + (tx0 + col)] = v;
        }
    }
}

// ---------------------------------------------------------------------------
// 1x1 conv over concat([c_new, m_new]) (128 ch) -> 64 ch, epilogue h = o*tanh(.)
// grid: (4096/256 n-chunks, 64/16 cout groups, B)
// ---------------------------------------------------------------------------
__global__ __launch_bounds__(256) void conv1x1_h_kernel(
    const float* __restrict__ cin, const float* __restrict__ min_,
    const float* __restrict__ wt, const float* __restrict__ bias,
    const float* __restrict__ ogate, float* __restrict__ hout)
{
    __shared__ __align__(16) float wlds[128][16];
    const int tid = threadIdx.x;
    const int n0  = blockIdx.x * 256;
    const int co0 = blockIdx.y * 16;
    const int b   = blockIdx.z;

    for (int i = tid; i < 2048; i += 256) {
        int q  = i >> 7;
        int ci = i & 127;
        wlds[ci][q] = wt[(co0 + q) * 128 + ci];
    }
    __syncthreads();

    const int n = n0 + tid;
    float acc[16];
#pragma unroll
    for (int q = 0; q < 16; ++q) acc[q] = 0.f;

    const float* cb = cin  + (long)b * HC * HWN + n;
    const float* mb = min_ + (long)b * HC * HWN + n;
#pragma unroll 2
    for (int ci = 0; ci < HC; ++ci) {
        float xv = cb[(long)ci * HWN];
#pragma unroll
        for (int q4 = 0; q4 < 4; ++q4) {
            float4 w4 = *(const float4*)&wlds[ci][q4 * 4];
            acc[q4 * 4 + 0] = fmaf(xv, w4.x, acc[q4 * 4 + 0]);
            acc[q4 * 4 + 1] = fmaf(xv, w4.y, acc[q4 * 4 + 1]);
            acc[q4 * 4 + 2] = fmaf(xv, w4.z, acc[q4 * 4 + 2]);
            acc[q4 * 4 + 3] = fmaf(xv, w4.w, acc[q4 * 4 + 3]);
        }
    }
#pragma unroll 2
    for (int ci = 0; ci < HC; ++ci) {
        float xv = mb[(long)ci * HWN];
#pragma unroll
        for (int q4 = 0; q4 < 4; ++q4) {
            float4 w4 = *(const float4*)&wlds[64 + ci][q4 * 4];
            acc[q4 * 4 + 0] = fmaf(xv, w4.x, acc[q4 * 4 + 0]);
            acc[q4 * 4 + 1] = fmaf(xv, w4.y, acc[q4 * 4 + 1]);
            acc[q4 * 4 + 2] = fmaf(xv, w4.z, acc[q4 * 4 + 2]);
            acc[q4 * 4 + 3] = fmaf(xv, w4.w, acc[q4 * 4 + 3]);
        }
    }

#pragma unroll
    for (int q = 0; q < 16; ++q) {
        long idx = ((long)b * HC + co0 + q) * HWN + n;
        hout[idx] = ogate[idx] * tanhf(acc[q] + bias[co0 + q]);
    }
}

// ---------------------------------------------------------------------------
// Elementwise gates: r,z,o,xr,xz plus products r*c and xr*m
// ---------------------------------------------------------------------------
__global__ __launch_bounds__(256) void gates_kernel(
    const float* __restrict__ A, const float* __restrict__ Bm,
    const float* __restrict__ h, const float* __restrict__ m,
    const float* __restrict__ c,
    const float* __restrict__ td_h, const float* __restrict__ td_m,
    const float* __restrict__ tg,
    float* __restrict__ r, float* __restrict__ xr, float* __restrict__ z,
    float* __restrict__ xz, float* __restrict__ o,
    float* __restrict__ rc, float* __restrict__ xm)
{
    const int i = blockIdx.x * 256 + threadIdx.x;     // < 2^20
    const int local = i & (HC * HWN - 1);
    const int b  = i >> 18;
    const int ch = (i >> 12) & 63;

    const float gate = sigmoidf_(tg[ch]);
    const float dh = expf(-td_h[ch]);
    const float dm = expf(-td_m[ch]);

    const float* Ab = A  + (long)b * 192 * HWN;
    const float* Bb = Bm + (long)b * 128 * HWN;
    const float hv = h[i], mv = m[i], cv = c[i];
    const float Ar = Ab[local];
    const float Az = Ab[local + 64 * HWN];
    const float Ao = Ab[local + 128 * HWN];
    const float Br = Bb[local];
    const float Bz = Bb[local + 64 * HWN];

    const float rv  = sigmoidf_(Ar * gate + hv * dh);
    const float zv  = sigmoidf_(Az * gate + hv * dh);
    const float ov  = sigmoidf_(Ao);
    const float xrv = sigmoidf_(Br * gate + mv * dm);
    const float xzv = sigmoidf_(Bz * gate + mv * dm);

    r[i] = rv; xr[i] = xrv; z[i] = zv; xz[i] = xzv; o[i] = ov;
    rc[i] = rv * cv; xm[i] = xrv * mv;
}

// c = z*c + (1-z)*gc (in place); m_out = xz*m_in + (1-xz)*gm
__global__ __launch_bounds__(256) void state_kernel(
    const float* __restrict__ z, const float* __restrict__ gc, float* __restrict__ c,
    const float* __restrict__ xz, const float* __restrict__ gm,
    const float* __restrict__ m_in, float* __restrict__ m_out)
{
    const int i = blockIdx.x * 256 + threadIdx.x;
    const float zv = z[i];
    c[i] = zv * c[i] + (1.f - zv) * gc[i];
    const float xzv = xz[i];
    m_out[i] = xzv * m_in[i] + (1.f - xzv) * gm[i];
}

__global__ __launch_bounds__(256) void qk_kernel(
    const float* __restrict__ r, const float* __restrict__ xr,
    const float* __restrict__ c1, const float* __restrict__ gc,
    const float* __restrict__ m1, const float* __restrict__ gm,
    float* __restrict__ q, float* __restrict__ k)
{
    const int i = blockIdx.x * 256 + threadIdx.x;
    const float rv = r[i], xv = xr[i];
    q[i] = 0.25f * (rv + xv + c1[i] + gc[i]);
    k[i] = 0.25f * (rv + xv + m1[i] + gm[i]);
}

// logits[b][cq][ck] = (1/64) * sum_n q[b,cq,n]*k[b,ck,n]
// grid 64 blocks: blk = b*16+cqg; thread: cq = cqg*4 + tid/64, ck = tid&63
__global__ __launch_bounds__(256) void logits_kernel(
    const float* __restrict__ q, const float* __restrict__ k, float* __restrict__ lg)
{
    const int blk = blockIdx.x;
    const int b  = blk >> 4;
    const int cq = (blk & 15) * 4 + (threadIdx.x >> 6);
    const int ck = threadIdx.x & 63;
    const float4* qr = (const float4*)(q + (long)(b * 64 + cq) * HWN);
    const float4* kr = (const float4*)(k + (long)(b * 64 + ck) * HWN);
    float acc = 0.f;
#pragma unroll 4
    for (int n = 0; n < HWN / 4; ++n) {
        float4 a = qr[n], bb = kr[n];
        acc = fmaf(a.x, bb.x, acc);
        acc = fmaf(a.y, bb.y, acc);
        acc = fmaf(a.z, bb.z, acc);
        acc = fmaf(a.w, bb.w, acc);
    }
    lg[(b * 64 + cq) * 64 + ck] = acc * (1.f / 64.f);
}

// softmax over last dim (64) ; one wave per row
__global__ void softmax_kernel(const float* __restrict__ lg, float* __restrict__ attn)
{
    const int row = blockIdx.x;     // 0..255 = (b,cq)
    const int lane = threadIdx.x;   // 0..63
    float v = lg[row * 64 + lane];
    float mx = v;
    for (int off = 32; off; off >>= 1) mx = fmaxf(mx, __shfl_xor(mx, off));
    float e = expf(v - mx);
    float s = e;
    for (int off = 32; off; off >>= 1) s += __shfl_xor(s, off);
    attn[row * 64 + lane] = e / s;
}

// out[b,t,c,n] = sum_d attn[b,c,d] * hs[t][b][d][n]
// grid: (b*8+t : 32, n-chunk : 16, c-group of 8 : 8)
__global__ __launch_bounds__(256) void out_kernel(
    const float* __restrict__ attn, const float* __restrict__ hs, float* __restrict__ outp)
{
    __shared__ __align__(16) float att_t[64][8];
    const int bt = blockIdx.x;
    const int b = bt >> 3, t = bt & 7;
    const int n0 = blockIdx.y * 256;
    const int c0 = blockIdx.z * 8;
    const int tid = threadIdx.x;

    for (int i = tid; i < 512; i += 256) {
        int d = i >> 3, j = i & 7;
        att_t[d][j] = attn[(b * 64 + c0 + j) * 64 + d];
    }
    __syncthreads();

    const int n = n0 + tid;
    float acc[8];
#pragma unroll
    for (int j = 0; j < 8; ++j) acc[j] = 0.f;

    const float* hsb = hs + (long)t * S_ELEMS + (long)b * HC * HWN + n;
#pragma unroll 4
    for (int d = 0; d < 64; ++d) {
        float vv = hsb[(long)d * HWN];
        float4 a0 = *(const float4*)&att_t[d][0];
        float4 a1 = *(const float4*)&att_t[d][4];
        acc[0] = fmaf(vv, a0.x, acc[0]);
        acc[1] = fmaf(vv, a0.y, acc[1]);
        acc[2] = fmaf(vv, a0.z, acc[2]);
        acc[3] = fmaf(vv, a0.w, acc[3]);
        acc[4] = fmaf(vv, a1.x, acc[4]);
        acc[5] = fmaf(vv, a1.y, acc[5]);
        acc[6] = fmaf(vv, a1.z, acc[6]);
        acc[7] = fmaf(vv, a1.w, acc[7]);
    }
    const long ob = ((long)(b * Tn + t) * HC + c0) * HWN + n;
#pragma unroll
    for (int j = 0; j < 8; ++j) outp[ob + (long)j * HWN] = acc[j];
}

// ---------------------------------------------------------------------------
extern "C" void kernel_launch(void* const* d_in, const int* in_sizes, int n_in,
                              void* d_out, int out_size, void* d_ws, size_t ws_size,
                              hipStream_t stream)
{
    const float* x = (const float*)d_in[0];
    const float* w_rzo[2] = {(const float*)d_in[1],  (const float*)d_in[12]};
    const float* b_rzo[2] = {(const float*)d_in[2],  (const float*)d_in[13]};
    const float* w_rz[2]  = {(const float*)d_in[3],  (const float*)d_in[14]};
    const float* b_rz[2]  = {(const float*)d_in[4],  (const float*)d_in[15]};
    const float* w_h[2]   = {(const float*)d_in[5],  (const float*)d_in[16]};
    const float* b_h[2]   = {(const float*)d_in[6],  (const float*)d_in[17]};
    const float* w_o[2]   = {(const float*)d_in[7],  (const float*)d_in[18]};
    const float* b_o[2]   = {(const float*)d_in[8],  (const float*)d_in[19]};
    const float* td_h[2]  = {(const float*)d_in[9],  (const float*)d_in[20]};
    const float* td_m[2]  = {(const float*)d_in[10], (const float*)d_in[21]};
    const float* tg[2]    = {(const float*)d_in[11], (const float*)d_in[22]};

    float* ws = (float*)d_ws;
    const long S = S_ELEMS;
    float* h0    = ws;            // ---- zero region: 6 slabs ----
    float* c0    = h0 + S;
    float* m0    = c0 + S;
    float* c1    = m0 + S;
    float* m1    = c1 + S;
    float* zslab = m1 + S;        // stays zero; h1 input at t=0
    float* Abuf  = zslab + S;     // 3S
    float* Bbuf  = Abuf + 3 * S;  // 2S
    float* rbuf  = Bbuf + 2 * S;
    float* xrbuf = rbuf + S;
    float* zbuf  = xrbuf + S;
    float* xzbuf = zbuf + S;
    float* obuf  = xzbuf + S;
    float* rcbuf = obuf + S;
    float* xmbuf = rcbuf + S;
    float* gcbuf = xmbuf + S;
    float* gmbuf = gcbuf + S;
    float* hsbuf = gmbuf + S;     // 8S : v sequence; doubles as layer-1 h state
    float* qbuf  = hsbuf + 8 * S;
    float* kbuf  = qbuf + S;
    float* lbuf  = kbuf + S;      // 16384
    float* attnb = lbuf + 16384;  // 16384

    hipMemsetAsync(h0, 0, (size_t)(6 * S) * sizeof(float), stream);

    const int sbX = Tn * 16 * HWN;  // x batch stride (elems)
    const int sbS = HC * HWN;       // state batch stride

    for (int t = 0; t < Tn; ++t) {
        const float* xt = x + (long)t * 16 * HWN;

        // ---------- layer 0 (inp = x_t, h=h0, c=c0, m_in=m1 -> m_out=m0) ----------
        conv3_kernel<12, 0><<<dim3(4, 16, 4), 256, 0, stream>>>(
            xt, 16, sbX, h0, h0, HC, sbS, w_rzo[0], b_rzo[0], Abuf, Abuf, 192);
        conv3_kernel<8, 0><<<dim3(4, 16, 4), 256, 0, stream>>>(
            xt, 16, sbX, m1, m1, HC, sbS, w_rz[0], b_rz[0], Bbuf, Bbuf, 128);
        gates_kernel<<<dim3(4096), 256, 0, stream>>>(Abuf, Bbuf, h0, m1, c0,
            td_h[0], td_m[0], tg[0], rbuf, xrbuf, zbuf, xzbuf, obuf, rcbuf, xmbuf);
        conv3_kernel<8, 1><<<dim3(4, 8, 8), 256, 0, stream>>>(
            xt, 16, sbX, rcbuf, xmbuf, HC, sbS, w_h[0], b_h[0], gcbuf, gmbuf, 64);
        state_kernel<<<dim3(4096), 256, 0, stream>>>(zbuf, gcbuf, c0, xzbuf, gmbuf, m1, m0);
        conv1x1_h_kernel<<<dim3(16, 4, 4), 256, 0, stream>>>(c0, m0, w_o[0], b_o[0], obuf, h0);

        // ---------- layer 1 (inp = h0, h=hs[t-1], c=c1, m_in=m0 -> m_out=m1) ------
        const float* h1prev = (t == 0) ? zslab : (hsbuf + (long)(t - 1) * S);
        float* h1out = hsbuf + (long)t * S;
        conv3_kernel<12, 0><<<dim3(4, 16, 4), 256, 0, stream>>>(
            h0, HC, sbS, h1prev, h1prev, HC, sbS, w_rzo[1], b_rzo[1], Abuf, Abuf, 192);
        conv3_kernel<8, 0><<<dim3(4, 16, 4), 256, 0, stream>>>(
            h0, HC, sbS, m0, m0, HC, sbS, w_rz[1], b_rz[1], Bbuf, Bbuf, 128);
        gates_kernel<<<dim3(4096), 256, 0, stream>>>(Abuf, Bbuf, h1prev, m0, c1,
            td_h[1], td_m[1], tg[1], rbuf, xrbuf, zbuf, xzbuf, obuf, rcbuf, xmbuf);
        conv3_kernel<8, 1><<<dim3(4, 8, 8), 256, 0, stream>>>(
            h0, HC, sbS, rcbuf, xmbuf, HC, sbS, w_h[1], b_h[1], gcbuf, gmbuf, 64);
        state_kernel<<<dim3(4096), 256, 0, stream>>>(zbuf, gcbuf, c1, xzbuf, gmbuf, m0, m1);
        conv1x1_h_kernel<<<dim3(16, 4, 4), 256, 0, stream>>>(c1, m1, w_o[1], b_o[1], obuf, h1out);
    }

    // ---------- attention ----------
    qk_kernel<<<dim3(4096), 256, 0, stream>>>(rbuf, xrbuf, c1, gcbuf, m1, gmbuf, qbuf, kbuf);
    logits_kernel<<<dim3(64), 256, 0, stream>>>(qbuf, kbuf, lbuf);
    softmax_kernel<<<dim3(256), 64, 0, stream>>>(lbuf, attnb);
    out_kernel<<<dim3(32, 16, 8), 256, 0, stream>>>(attnb, hsbuf, (float*)d_out);
}

// Round 2
// 4560.545 us; speedup vs baseline: 2.9935x; 2.9935x over previous
//
#include <hip/hip_runtime.h>
#include <hip/hip_fp16.h>
#include <math.h>

#define HWN 4096
#define Bn 4
#define Tn 8
#define HC 64
#define S_ELEMS (Bn*HC*HWN)   // 1048576 elems = 4 MB
#define CIP 40                // padded ci stride in LDS (40 f16 = 80 B = 20 banks)

typedef __attribute__((ext_vector_type(8))) _Float16 f16x8;
typedef __attribute__((ext_vector_type(4))) float floatx4;

__device__ __forceinline__ float sigmoidf_(float v) { return 1.f / (1.f + expf(-v)); }

// ---------------------------------------------------------------------------
// Weight prep: fp32 [Cout][Ctot][3][3] -> f16 hi/lo planes in A-fragment-
// swizzled order: [plane][kk][chunk][cog][lane][j]  (lane reads 8 contiguous
// f16 = one global_load_dwordx4 per fragment).
// A-frag layout (16x16x32): A[m=lane&15][k=quad*8+j]; m=co_local, k=ci_local.
// ---------------------------------------------------------------------------
__global__ __launch_bounds__(256) void prep_w_kernel(
    const float* __restrict__ W, __half* __restrict__ dst,
    int Ctot, int Cout, int nch)
{
    const int ncog = Cout >> 4;
    const long total = (long)9 * nch * ncog * 512;   // per plane, f16 elems
    for (long i = (long)blockIdx.x * 256 + threadIdx.x; i < total;
         i += (long)gridDim.x * 256) {
        int j    = (int)(i & 7);
        int lane = (int)((i >> 3) & 63);
        long r   = i >> 9;
        int f = (int)(r % ncog); r /= ncog;
        int c = (int)(r % nch);  r /= nch;
        int kk = (int)r;
        int co = f * 16 + (lane & 15);
        int ci = c * 32 + (lane >> 4) * 8 + j;
        float v = (ci < Ctot) ? W[((long)co * Ctot + ci) * 9 + kk] : 0.f;
        _Float16 hi = (_Float16)v;
        _Float16 lo = (_Float16)(v - (float)hi);
        dst[i]         = *(__half*)&hi;
        dst[total + i] = *(__half*)&lo;
    }
}

// ---------------------------------------------------------------------------
// MFMA implicit-GEMM 3x3 SAME conv, fp16-split-2 (3 products), fp32 I/O.
// Input = concat([in1 (C1 ch), in2 (Ctot-C1 ch)]).
// Block: 256 thr = 4 waves. Tile: M=64 couts x N=256 px (16x16 spatial).
// Wave: M=64 x N=64 (4 rows of 16 px). grid=(16 tiles, Cout/64, B or 2B dual).
// B staged in LDS as [plane][yh][xh][ci] (halo 18x18, ci-contig for b128).
// A frags loaded straight from swizzled global (L2-resident, no LDS).
// ---------------------------------------------------------------------------
template<int TANH>
__global__ __launch_bounds__(256) void conv3m_kernel(
    const float* __restrict__ in1, int C1, long sb1,
    const float* __restrict__ in2a, const float* __restrict__ in2b, long sb2,
    int Ctot, int nch,
    const __half* __restrict__ Wg, const float* __restrict__ bias,
    float* __restrict__ outa, float* __restrict__ outb, int Cout)
{
    __shared__ __align__(16) _Float16 ldsB[2][18][18][CIP];

    const int tid  = threadIdx.x;
    const int ty0  = (blockIdx.x >> 2) * 16;
    const int tx0  = (blockIdx.x & 3) * 16;
    const int co0  = blockIdx.y * 64;
    const int b     = blockIdx.z & 3;
    const int which = blockIdx.z >> 2;
    const float* in2 = which ? in2b : in2a;
    float*       out = which ? outb : outa;

    const int lane = tid & 63;
    const int wv   = tid >> 6;
    const int tl   = lane & 15;
    const int quad = lane >> 4;
    const int ncog = Cout >> 4;
    const long wplane = (long)9 * nch * ncog * 512;
    const _Float16* Wf = (const _Float16*)Wg;

    floatx4 acc[4][4];
#pragma unroll
    for (int f = 0; f < 4; ++f)
#pragma unroll
        for (int g = 0; g < 4; ++g) acc[f][g] = (floatx4){0.f, 0.f, 0.f, 0.f};

    const float* in1b  = in1 + (long)b * sb1;
    const float* in2b_ = in2 + (long)b * sb2;

    for (int c = 0; c < nch; ++c) {
        __syncthreads();
        const int c0 = c * 32;
        // stage 32 input channels of an 18x18 halo tile, split to f16 hi/lo
        for (int i = tid; i < 32 * 324; i += 256) {
            const int ci  = i / 324;
            const int rem = i - ci * 324;
            const int yh  = rem / 18;
            const int xh  = rem - yh * 18;
            const int y = ty0 + yh - 1, x = tx0 + xh - 1;
            const int cg = c0 + ci;
            float v = 0.f;
            if (cg < Ctot && (unsigned)y < 64u && (unsigned)x < 64u) {
                const float* src = (cg < C1) ? (in1b + (long)cg * HWN)
                                             : (in2b_ + (long)(cg - C1) * HWN);
                v = src[y * 64 + x];
            }
            _Float16 hi = (_Float16)v;
            _Float16 lo = (_Float16)(v - (float)hi);
            ldsB[0][yh][xh][ci] = hi;
            ldsB[1][yh][xh][ci] = lo;
        }
        __syncthreads();

        for (int kk = 0; kk < 9; ++kk) {
            const int ky = kk / 3, kx = kk - ky * 3;
            const long wo = ((long)(kk * nch + c) * ncog + (co0 >> 4)) * 512 + lane * 8;
            const _Float16* wp = Wf + wo;
            f16x8 ah[4], al[4], bh[4], bl[4];
#pragma unroll
            for (int f = 0; f < 4; ++f) {
                ah[f] = *(const f16x8*)(wp + (long)f * 512);
                al[f] = *(const f16x8*)(wp + wplane + (long)f * 512);
            }
#pragma unroll
            for (int g = 0; g < 4; ++g) {
                const _Float16* pB = &ldsB[0][wv * 4 + g + ky][tl + kx][quad * 8];
                bh[g] = *(const f16x8*)pB;
                bl[g] = *(const f16x8*)(pB + 18 * 18 * CIP);
            }
#pragma unroll
            for (int f = 0; f < 4; ++f)
#pragma unroll
                for (int g = 0; g < 4; ++g) {
                    acc[f][g] = __builtin_amdgcn_mfma_f32_16x16x32_f16(ah[f], bh[g], acc[f][g], 0, 0, 0);
                    acc[f][g] = __builtin_amdgcn_mfma_f32_16x16x32_f16(ah[f], bl[g], acc[f][g], 0, 0, 0);
                    acc[f][g] = __builtin_amdgcn_mfma_f32_16x16x32_f16(al[f], bh[g], acc[f][g], 0, 0, 0);
                }
        }
    }

    // epilogue: C/D layout col(n)=lane&15, row(m)=quad*4+reg
    const long ob = (long)b * Cout * HWN;
#pragma unroll
    for (int f = 0; f < 4; ++f) {
        const int co = co0 + f * 16 + quad * 4;
#pragma unroll
        for (int g = 0; g < 4; ++g) {
            const int py = ty0 + wv * 4 + g;
            const int px = tx0 + tl;
#pragma unroll
            for (int r = 0; r < 4; ++r) {
                float v = acc[f][g][r] + bias[co + r];
                if (TANH) v = tanhf(v);
                out[ob + (long)(co + r) * HWN + py * 64 + px] = v;
            }
        }
    }
}

// ---------------------------------------------------------------------------
// 1x1 conv over concat([c_new, m_new]) (128 ch) -> 64 ch, epilogue h = o*tanh(.)
// ---------------------------------------------------------------------------
__global__ __launch_bounds__(256) void conv1x1_h_kernel(
    const float* __restrict__ cin, const float* __restrict__ min_,
    const float* __restrict__ wt, const float* __restrict__ bias,
    const float* __restrict__ ogate, float* __restrict__ hout)
{
    __shared__ __align__(16) float wlds[128][16];
    const int tid = threadIdx.x;
    const int n0  = blockIdx.x * 256;
    const int co0 = blockIdx.y * 16;
    const int b   = blockIdx.z;

    for (int i = tid; i < 2048; i += 256) {
        int q  = i >> 7;
        int ci = i & 127;
        wlds[ci][q] = wt[(co0 + q) * 128 + ci];
    }
    __syncthreads();

    const int n = n0 + tid;
    float acc[16];
#pragma unroll
    for (int q = 0; q < 16; ++q) acc[q] = 0.f;

    const float* cb = cin  + (long)b * HC * HWN + n;
    const float* mb = min_ + (long)b * HC * HWN + n;
#pragma unroll 2
    for (int ci = 0; ci < HC; ++ci) {
        float xv = cb[(long)ci * HWN];
#pragma unroll
        for (int q4 = 0; q4 < 4; ++q4) {
            float4 w4 = *(const float4*)&wlds[ci][q4 * 4];
            acc[q4 * 4 + 0] = fmaf(xv, w4.x, acc[q4 * 4 + 0]);
            acc[q4 * 4 + 1] = fmaf(xv, w4.y, acc[q4 * 4 + 1]);
            acc[q4 * 4 + 2] = fmaf(xv, w4.z, acc[q4 * 4 + 2]);
            acc[q4 * 4 + 3] = fmaf(xv, w4.w, acc[q4 * 4 + 3]);
        }
    }
#pragma unroll 2
    for (int ci = 0; ci < HC; ++ci) {
        float xv = mb[(long)ci * HWN];
#pragma unroll
        for (int q4 = 0; q4 < 4; ++q4) {
            float4 w4 = *(const float4*)&wlds[64 + ci][q4 * 4];
            acc[q4 * 4 + 0] = fmaf(xv, w4.x, acc[q4 * 4 + 0]);
            acc[q4 * 4 + 1] = fmaf(xv, w4.y, acc[q4 * 4 + 1]);
            acc[q4 * 4 + 2] = fmaf(xv, w4.z, acc[q4 * 4 + 2]);
            acc[q4 * 4 + 3] = fmaf(xv, w4.w, acc[q4 * 4 + 3]);
        }
    }

#pragma unroll
    for (int q = 0; q < 16; ++q) {
        long idx = ((long)b * HC + co0 + q) * HWN + n;
        hout[idx] = ogate[idx] * tanhf(acc[q] + bias[co0 + q]);
    }
}

// ---------------------------------------------------------------------------
__global__ __launch_bounds__(256) void gates_kernel(
    const float* __restrict__ A, const float* __restrict__ Bm,
    const float* __restrict__ h, const float* __restrict__ m,
    const float* __restrict__ c,
    const float* __restrict__ td_h, const float* __restrict__ td_m,
    const float* __restrict__ tg,
    float* __restrict__ r, float* __restrict__ xr, float* __restrict__ z,
    float* __restrict__ xz, float* __restrict__ o,
    float* __restrict__ rc, float* __restrict__ xm)
{
    const int i = blockIdx.x * 256 + threadIdx.x;     // < 2^20
    const int local = i & (HC * HWN - 1);
    const int b  = i >> 18;
    const int ch = (i >> 12) & 63;

    const float gate = sigmoidf_(tg[ch]);
    const float dh = expf(-td_h[ch]);
    const float dm = expf(-td_m[ch]);

    const float* Ab = A  + (long)b * 192 * HWN;
    const float* Bb = Bm + (long)b * 128 * HWN;
    const float hv = h[i], mv = m[i], cv = c[i];
    const float Ar = Ab[local];
    const float Az = Ab[local + 64 * HWN];
    const float Ao = Ab[local + 128 * HWN];
    const float Br = Bb[local];
    const float Bz = Bb[local + 64 * HWN];

    const float rv  = sigmoidf_(Ar * gate + hv * dh);
    const float zv  = sigmoidf_(Az * gate + hv * dh);
    const float ov  = sigmoidf_(Ao);
    const float xrv = sigmoidf_(Br * gate + mv * dm);
    const float xzv = sigmoidf_(Bz * gate + mv * dm);

    r[i] = rv; xr[i] = xrv; z[i] = zv; xz[i] = xzv; o[i] = ov;
    rc[i] = rv * cv; xm[i] = xrv * mv;
}

__global__ __launch_bounds__(256) void state_kernel(
    const float* __restrict__ z, const float* __restrict__ gc, float* __restrict__ c,
    const float* __restrict__ xz, const float* __restrict__ gm,
    const float* __restrict__ m_in, float* __restrict__ m_out)
{
    const int i = blockIdx.x * 256 + threadIdx.x;
    const float zv = z[i];
    c[i] = zv * c[i] + (1.f - zv) * gc[i];
    const float xzv = xz[i];
    m_out[i] = xzv * m_in[i] + (1.f - xzv) * gm[i];
}

__global__ __launch_bounds__(256) void qk_kernel(
    const float* __restrict__ r, const float* __restrict__ xr,
    const float* __restrict__ c1, const float* __restrict__ gc,
    const float* __restrict__ m1, const float* __restrict__ gm,
    float* __restrict__ q, float* __restrict__ k)
{
    const int i = blockIdx.x * 256 + threadIdx.x;
    const float rv = r[i], xv = xr[i];
    q[i] = 0.25f * (rv + xv + c1[i] + gc[i]);
    k[i] = 0.25f * (rv + xv + m1[i] + gm[i]);
}

__global__ __launch_bounds__(256) void logits_kernel(
    const float* __restrict__ q, const float* __restrict__ k, float* __restrict__ lg)
{
    const int blk = blockIdx.x;
    const int b  = blk >> 4;
    const int cq = (blk & 15) * 4 + (threadIdx.x >> 6);
    const int ck = threadIdx.x & 63;
    const float4* qr = (const float4*)(q + (long)(b * 64 + cq) * HWN);
    const float4* kr = (const float4*)(k + (long)(b * 64 + ck) * HWN);
    float acc = 0.f;
#pragma unroll 4
    for (int n = 0; n < HWN / 4; ++n) {
        float4 a = qr[n], bb = kr[n];
        acc = fmaf(a.x, bb.x, acc);
        acc = fmaf(a.y, bb.y, acc);
        acc = fmaf(a.z, bb.z, acc);
        acc = fmaf(a.w, bb.w, acc);
    }
    lg[(b * 64 + cq) * 64 + ck] = acc * (1.f / 64.f);
}

__global__ void softmax_kernel(const float* __restrict__ lg, float* __restrict__ attn)
{
    const int row = blockIdx.x;     // 0..255 = (b,cq)
    const int lane = threadIdx.x;   // 0..63
    float v = lg[row * 64 + lane];
    float mx = v;
    for (int off = 32; off; off >>= 1) mx = fmaxf(mx, __shfl_xor(mx, off));
    float e = expf(v - mx);
    float s = e;
    for (int off = 32; off; off >>= 1) s += __shfl_xor(s, off);
    attn[row * 64 + lane] = e / s;
}

__global__ __launch_bounds__(256) void out_kernel(
    const float* __restrict__ attn, const float* __restrict__ hs, float* __restrict__ outp)
{
    __shared__ __align__(16) float att_t[64][8];
    const int bt = blockIdx.x;
    const int b = bt >> 3, t = bt & 7;
    const int n0 = blockIdx.y * 256;
    const int c0 = blockIdx.z * 8;
    const int tid = threadIdx.x;

    for (int i = tid; i < 512; i += 256) {
        int d = i >> 3, j = i & 7;
        att_t[d][j] = attn[(b * 64 + c0 + j) * 64 + d];
    }
    __syncthreads();

    const int n = n0 + tid;
    float acc[8];
#pragma unroll
    for (int j = 0; j < 8; ++j) acc[j] = 0.f;

    const float* hsb = hs + (long)t * S_ELEMS + (long)b * HC * HWN + n;
#pragma unroll 4
    for (int d = 0; d < 64; ++d) {
        float vv = hsb[(long)d * HWN];
        float4 a0 = *(const float4*)&att_t[d][0];
        float4 a1 = *(const float4*)&att_t[d][4];
        acc[0] = fmaf(vv, a0.x, acc[0]);
        acc[1] = fmaf(vv, a0.y, acc[1]);
        acc[2] = fmaf(vv, a0.z, acc[2]);
        acc[3] = fmaf(vv, a0.w, acc[3]);
        acc[4] = fmaf(vv, a1.x, acc[4]);
        acc[5] = fmaf(vv, a1.y, acc[5]);
        acc[6] = fmaf(vv, a1.z, acc[6]);
        acc[7] = fmaf(vv, a1.w, acc[7]);
    }
    const long ob = ((long)(b * Tn + t) * HC + c0) * HWN + n;
#pragma unroll
    for (int j = 0; j < 8; ++j) outp[ob + (long)j * HWN] = acc[j];
}

// ---------------------------------------------------------------------------
extern "C" void kernel_launch(void* const* d_in, const int* in_sizes, int n_in,
                              void* d_out, int out_size, void* d_ws, size_t ws_size,
                              hipStream_t stream)
{
    const float* x = (const float*)d_in[0];
    const float* w_rzo[2] = {(const float*)d_in[1],  (const float*)d_in[12]};
    const float* b_rzo[2] = {(const float*)d_in[2],  (const float*)d_in[13]};
    const float* w_rz[2]  = {(const float*)d_in[3],  (const float*)d_in[14]};
    const float* b_rz[2]  = {(const float*)d_in[4],  (const float*)d_in[15]};
    const float* w_h[2]   = {(const float*)d_in[5],  (const float*)d_in[16]};
    const float* b_h[2]   = {(const float*)d_in[6],  (const float*)d_in[17]};
    const float* w_o[2]   = {(const float*)d_in[7],  (const float*)d_in[18]};
    const float* b_o[2]   = {(const float*)d_in[8],  (const float*)d_in[19]};
    const float* td_h[2]  = {(const float*)d_in[9],  (const float*)d_in[20]};
    const float* td_m[2]  = {(const float*)d_in[10], (const float*)d_in[21]};
    const float* tg[2]    = {(const float*)d_in[11], (const float*)d_in[22]};

    float* ws = (float*)d_ws;
    const long S = S_ELEMS;
    float* h0    = ws;            // ---- zero region: 6 slabs ----
    float* c0    = h0 + S;
    float* m0    = c0 + S;
    float* c1    = m0 + S;
    float* m1    = c1 + S;
    float* zslab = m1 + S;        // stays zero; h1 input at t=0
    float* Abuf  = zslab + S;     // 3S
    float* Bbuf  = Abuf + 3 * S;  // 2S
    float* rbuf  = Bbuf + 2 * S;
    float* xrbuf = rbuf + S;
    float* zbuf  = xrbuf + S;
    float* xzbuf = zbuf + S;
    float* obuf  = xzbuf + S;
    float* rcbuf = obuf + S;
    float* xmbuf = rcbuf + S;
    float* gcbuf = xmbuf + S;
    float* gmbuf = gcbuf + S;
    float* hsbuf = gmbuf + S;     // 8S : v sequence; doubles as layer-1 h state
    float* qbuf  = hsbuf + 8 * S;
    float* kbuf  = qbuf + S;
    float* lbuf  = kbuf + S;      // 16384
    float* attnb = lbuf + 16384;  // 16384

    // swizzled split weights (f16), after the float region
    __half* wA0 = (__half*)(attnb + 16384);
    __half* wB0 = wA0 + 2 * 331776 / 2;   // A0: 2 planes * 165888... sizes below
    // sizes per conv (total f16 incl both planes) = 2*9*nch*ncog*512
    // A0: nch=3,ncog=12 -> 331776 ; B0: 221184 ; H0: 110592
    // A1: nch=4,ncog=12 -> 442368 ; B1: 294912 ; H1: 147456
    wB0 = wA0 + 331776;
    __half* wH0 = wB0 + 221184;
    __half* wA1 = wH0 + 110592;
    __half* wB1 = wA1 + 442368;
    __half* wH1 = wB1 + 294912;

    hipMemsetAsync(h0, 0, (size_t)(6 * S) * sizeof(float), stream);

    prep_w_kernel<<<512, 256, 0, stream>>>(w_rzo[0], wA0, 80, 192, 3);
    prep_w_kernel<<<512, 256, 0, stream>>>(w_rz[0],  wB0, 80, 128, 3);
    prep_w_kernel<<<512, 256, 0, stream>>>(w_h[0],   wH0, 80,  64, 3);
    prep_w_kernel<<<512, 256, 0, stream>>>(w_rzo[1], wA1, 128, 192, 4);
    prep_w_kernel<<<512, 256, 0, stream>>>(w_rz[1],  wB1, 128, 128, 4);
    prep_w_kernel<<<512, 256, 0, stream>>>(w_h[1],   wH1, 128, 64, 4);

    const long sbX = (long)Tn * 16 * HWN;  // x batch stride (elems)
    const long sbS = (long)HC * HWN;       // state batch stride

    for (int t = 0; t < Tn; ++t) {
        const float* xt = x + (long)t * 16 * HWN;

        // ---------- layer 0 (inp = x_t, h=h0, c=c0, m_in=m1 -> m_out=m0) ----------
        conv3m_kernel<0><<<dim3(16, 3, 4), 256, 0, stream>>>(
            xt, 16, sbX, h0, h0, sbS, 80, 3, wA0, b_rzo[0], Abuf, Abuf, 192);
        conv3m_kernel<0><<<dim3(16, 2, 4), 256, 0, stream>>>(
            xt, 16, sbX, m1, m1, sbS, 80, 3, wB0, b_rz[0], Bbuf, Bbuf, 128);
        gates_kernel<<<dim3(4096), 256, 0, stream>>>(Abuf, Bbuf, h0, m1, c0,
            td_h[0], td_m[0], tg[0], rbuf, xrbuf, zbuf, xzbuf, obuf, rcbuf, xmbuf);
        conv3m_kernel<1><<<dim3(16, 1, 8), 256, 0, stream>>>(
            xt, 16, sbX, rcbuf, xmbuf, sbS, 80, 3, wH0, b_h[0], gcbuf, gmbuf, 64);
        state_kernel<<<dim3(4096), 256, 0, stream>>>(zbuf, gcbuf, c0, xzbuf, gmbuf, m1, m0);
        conv1x1_h_kernel<<<dim3(16, 4, 4), 256, 0, stream>>>(c0, m0, w_o[0], b_o[0], obuf, h0);

        // ---------- layer 1 (inp = h0, h=hs[t-1], c=c1, m_in=m0 -> m_out=m1) ------
        const float* h1prev = (t == 0) ? zslab : (hsbuf + (long)(t - 1) * S);
        float* h1out = hsbuf + (long)t * S;
        conv3m_kernel<0><<<dim3(16, 3, 4), 256, 0, stream>>>(
            h0, 64, sbS, h1prev, h1prev, sbS, 128, 4, wA1, b_rzo[1], Abuf, Abuf, 192);
        conv3m_kernel<0><<<dim3(16, 2, 4), 256, 0, stream>>>(
            h0, 64, sbS, m0, m0, sbS, 128, 4, wB1, b_rz[1], Bbuf, Bbuf, 128);
        gates_kernel<<<dim3(4096), 256, 0, stream>>>(Abuf, Bbuf, h1prev, m0, c1,
            td_h[1], td_m[1], tg[1], rbuf, xrbuf, zbuf, xzbuf, obuf, rcbuf, xmbuf);
        conv3m_kernel<1><<<dim3(16, 1, 8), 256, 0, stream>>>(
            h0, 64, sbS, rcbuf, xmbuf, sbS, 128, 4, wH1, b_h[1], gcbuf, gmbuf, 64);
        state_kernel<<<dim3(4096), 256, 0, stream>>>(zbuf, gcbuf, c1, xzbuf, gmbuf, m0, m1);
        conv1x1_h_kernel<<<dim3(16, 4, 4), 256, 0, stream>>>(c1, m1, w_o[1], b_o[1], obuf, h1out);
    }

    // ---------- attention ----------
    qk_kernel<<<dim3(4096), 256, 0, stream>>>(rbuf, xrbuf, c1, gcbuf, m1, gmbuf, qbuf, kbuf);
    logits_kernel<<<dim3(64), 256, 0, stream>>>(qbuf, kbuf, lbuf);
    softmax_kernel<<<dim3(256), 64, 0, stream>>>(lbuf, attnb);
    out_kernel<<<dim3(32, 16, 8), 256, 0, stream>>>(attnb, hsbuf, (float*)d_out);
}

// Round 5
// 1699.009 us; speedup vs baseline: 8.0352x; 2.6842x over previous
//
#include <hip/hip_runtime.h>
#include <math.h>

#define HWN 4096
#define Bn 4
#define Tn 8

typedef __attribute__((ext_vector_type(8))) _Float16 f16x8;
typedef __attribute__((ext_vector_type(4))) float floatx4;

__device__ __forceinline__ float sigmoidf_(float v) { return 1.f / (1.f + expf(-v)); }

// split 8 fp32 -> f16 hi/lo vectors (value = hi + lo, ~22-bit effective)
__device__ __forceinline__ void split8(const float* vv, f16x8* hi, f16x8* lo) {
#pragma unroll
    for (int j = 0; j < 8; ++j) {
        _Float16 h = (_Float16)vv[j];
        (*hi)[j] = h;
        (*lo)[j] = (_Float16)(vv[j] - (float)h);
    }
}

// ---------------------------------------------------------------------------
// Weight prep: fp32 [Cout][Ctot][KK] -> A-fragment-swizzled split-f16:
// [plane][kk][chunk][cog][lane][j]; lane frag = 8 contiguous f16 (dwordx4).
// A-frag (16x16x32): A[m=lane&15][k=(lane>>4)*8+j].
// ---------------------------------------------------------------------------
__global__ __launch_bounds__(256) void prep_w_kernel(
    const float* __restrict__ W, _Float16* __restrict__ dst,
    int Ctot, int Cout, int nch, int KK)
{
    const int ncog = Cout >> 4;
    const long total = (long)KK * nch * ncog * 512;
    for (long i = (long)blockIdx.x * 256 + threadIdx.x; i < total;
         i += (long)gridDim.x * 256) {
        int j    = (int)(i & 7);
        int lane = (int)((i >> 3) & 63);
        long r   = i >> 9;
        int f = (int)(r % ncog); r /= ncog;
        int c = (int)(r % nch);  r /= nch;
        int kk = (int)r;
        int co = f * 16 + (lane & 15);
        int ci = c * 32 + (lane >> 4) * 8 + j;
        float v = (ci < Ctot) ? W[((long)co * Ctot + ci) * KK + kk] : 0.f;
        _Float16 hi = (_Float16)v;
        dst[i]         = hi;
        dst[total + i] = (_Float16)(v - (float)hi);
    }
}

// x fp32 [b][t][16][4096] -> x_cl fp32 [t][b][px][16]
__global__ __launch_bounds__(256) void prep_x_kernel(
    const float* __restrict__ x, float* __restrict__ xcl)
{
    const int i = blockIdx.x * 256 + threadIdx.x;     // 131072 total
    const int px = i & 4095;
    const int t  = (i >> 12) & 7;
    const int b  = i >> 15;
    float* d = xcl + (((long)t * Bn + b) * HWN + px) * 16;
#pragma unroll
    for (int ch = 0; ch < 16; ++ch)
        d[ch] = x[((long)(b * 8 + t) * 16 + ch) * HWN + px];
}

// ---------------------------------------------------------------------------
// MFMA implicit-GEMM 3x3 SAME conv. Activations fp32 channels-last; hi/lo
// f16 split happens during LDS staging (round-2-verified numerics).
// EPI=0: plain conv (merged A/B dispatch: which = blockIdx.y >= nA).
// EPI=1: H-conv: tanh + fused state update (+ q/k on last cell);
//        which = blockIdx.z>>2 selects {rc,z,c}->c_new vs {xm,xz,m}->m_new.
// Block 256 thr = 4 waves; tile M = NF*16 couts x N = 256 px (16x16 spatial).
// LDS tile [18][18][plane][40] (halo, ci-contiguous for ds_read_b128).
// ---------------------------------------------------------------------------
template<int EPI, int NF>
__global__ __launch_bounds__(256) void conv3m(
    const float* __restrict__ in1, int C1,
    const float* __restrict__ in2a, const float* __restrict__ in2b,
    int Ctot, int nch,
    const _Float16* __restrict__ wA, const float* __restrict__ biasA,
    float* outA, int CoutA, int ncogA,
    const _Float16* __restrict__ wB, const float* __restrict__ biasB,
    float* outB, int CoutB, int ncogB, int nA,
    const float* zA, const float* zB,
    const float* sA, const float* sB,
    const float* rten, const float* xrten,
    float* qout, float* kout, int last)
{
    __shared__ __align__(16) _Float16 ldsB[18][18][2][40];

    const int tid = threadIdx.x;
    const int ty0 = (blockIdx.x >> 2) * 16;
    const int tx0 = (blockIdx.x & 3) * 16;
    const int b   = blockIdx.z & 3;
    const int which = (EPI == 1) ? (int)(blockIdx.z >> 2)
                                 : (blockIdx.y >= (unsigned)nA ? 1 : 0);

    const float*    in2  = which ? in2b : in2a;
    const _Float16* Wf   = which ? wB : wA;
    const float*    bias = which ? biasB : biasA;
    float*          outp = which ? outB : outA;
    const int Cout = which ? CoutB : CoutA;
    const int ncog = which ? ncogB : ncogA;
    const int cog0 = (EPI == 1) ? blockIdx.y * NF
                   : (which ? (blockIdx.y - nA) * NF : blockIdx.y * NF);
    const int co0  = cog0 * 16;

    const int lane = tid & 63, wv = tid >> 6, tl = lane & 15, quad = lane >> 4;
    const int C2 = Ctot - C1;
    const long wplane = (long)9 * nch * ncog * 512;
    const float* in1b  = in1 + (long)b * HWN * C1;
    const float* in2bb = in2 + (long)b * HWN * C2;

    floatx4 acc[NF][4];
#pragma unroll
    for (int f = 0; f < NF; ++f)
#pragma unroll
        for (int g = 0; g < 4; ++g) acc[f][g] = (floatx4){0.f, 0.f, 0.f, 0.f};

    for (int c = 0; c < nch; ++c) {
        __syncthreads();
        const int c0 = c * 32;
        for (int i = tid; i < 1296; i += 256) {
            const int pxh = i >> 2, cig = i & 3;
            const int yh = pxh / 18, xh = pxh - yh * 18;
            const int y = ty0 + yh - 1, x = tx0 + xh - 1;
            const int ch = c0 + cig * 8;
            f16x8 vh = {0, 0, 0, 0, 0, 0, 0, 0};
            f16x8 vl = {0, 0, 0, 0, 0, 0, 0, 0};
            if (ch < Ctot && (unsigned)y < 64u && (unsigned)x < 64u) {
                const float* src; long off;
                if (ch < C1) { src = in1b;  off = (long)(y * 64 + x) * C1 + ch; }
                else         { src = in2bb; off = (long)(y * 64 + x) * C2 + ch - C1; }
                float4 a  = *(const float4*)(src + off);
                float4 b4 = *(const float4*)(src + off + 4);
                float vv[8] = {a.x, a.y, a.z, a.w, b4.x, b4.y, b4.z, b4.w};
                split8(vv, &vh, &vl);
            }
            *(f16x8*)&ldsB[yh][xh][0][cig * 8] = vh;
            *(f16x8*)&ldsB[yh][xh][1][cig * 8] = vl;
        }
        __syncthreads();

        for (int kk = 0; kk < 9; ++kk) {
            const int ky = kk / 3, kx = kk - ky * 3;
            const long wo = ((long)(kk * nch + c) * ncog + cog0) * 512 + lane * 8;
            f16x8 ah[NF], al[NF], bh[4], bl[4];
#pragma unroll
            for (int f = 0; f < NF; ++f) {
                ah[f] = *(const f16x8*)(Wf + wo + (long)f * 512);
                al[f] = *(const f16x8*)(Wf + wplane + wo + (long)f * 512);
            }
#pragma unroll
            for (int g = 0; g < 4; ++g) {
                const _Float16* pB = &ldsB[wv * 4 + g + ky][tl + kx][0][quad * 8];
                bh[g] = *(const f16x8*)pB;
                bl[g] = *(const f16x8*)(pB + 40);
            }
#pragma unroll
            for (int f = 0; f < NF; ++f)
#pragma unroll
                for (int g = 0; g < 4; ++g) {
                    acc[f][g] = __builtin_amdgcn_mfma_f32_16x16x32_f16(ah[f], bh[g], acc[f][g], 0, 0, 0);
                    acc[f][g] = __builtin_amdgcn_mfma_f32_16x16x32_f16(ah[f], bl[g], acc[f][g], 0, 0, 0);
                    acc[f][g] = __builtin_amdgcn_mfma_f32_16x16x32_f16(al[f], bh[g], acc[f][g], 0, 0, 0);
                }
        }
    }

    // epilogue: C/D layout col(px)=lane&15, row(co)=quad*4+reg
    if (EPI == 0) {
        const long obb = (long)b * HWN * Cout;
#pragma unroll
        for (int f = 0; f < NF; ++f) {
            const int co = co0 + f * 16 + quad * 4;
#pragma unroll
            for (int g = 0; g < 4; ++g) {
                const long px = (long)(ty0 + wv * 4 + g) * 64 + tx0 + tl;
                float4 v;
                v.x = acc[f][g][0] + bias[co + 0];
                v.y = acc[f][g][1] + bias[co + 1];
                v.z = acc[f][g][2] + bias[co + 2];
                v.w = acc[f][g][3] + bias[co + 3];
                *(float4*)(outp + obb + px * Cout + co) = v;
            }
        }
    } else {
        const float* zt = which ? zB : zA;
        const float* st = which ? sB : sA;
        float* qk = which ? kout : qout;
#pragma unroll
        for (int f = 0; f < NF; ++f) {
            const int co = co0 + f * 16 + quad * 4;
#pragma unroll
            for (int g = 0; g < 4; ++g) {
                const long px = (long)(ty0 + wv * 4 + g) * 64 + tx0 + tl;
                const long off = (long)b * HWN * 64 + px * 64 + co;
                float4 zv = *(const float4*)(zt + off);
                float4 sv = *(const float4*)(st + off);
                float gv[4], cn[4];
                gv[0] = tanhf(acc[f][g][0] + bias[co + 0]);
                gv[1] = tanhf(acc[f][g][1] + bias[co + 1]);
                gv[2] = tanhf(acc[f][g][2] + bias[co + 2]);
                gv[3] = tanhf(acc[f][g][3] + bias[co + 3]);
                cn[0] = zv.x * sv.x + (1.f - zv.x) * gv[0];
                cn[1] = zv.y * sv.y + (1.f - zv.y) * gv[1];
                cn[2] = zv.z * sv.z + (1.f - zv.z) * gv[2];
                cn[3] = zv.w * sv.w + (1.f - zv.w) * gv[3];
                *(float4*)(outp + off) = *(float4*)cn;
                if (last) {
                    float4 rv = *(const float4*)(rten + off);
                    float4 xv = *(const float4*)(xrten + off);
                    qk[((long)(b * 64) + co + 0) * HWN + px] = 0.25f * (rv.x + xv.x + cn[0] + gv[0]);
                    qk[((long)(b * 64) + co + 1) * HWN + px] = 0.25f * (rv.y + xv.y + cn[1] + gv[1]);
                    qk[((long)(b * 64) + co + 2) * HWN + px] = 0.25f * (rv.z + xv.z + cn[2] + gv[2]);
                    qk[((long)(b * 64) + co + 3) * HWN + px] = 0.25f * (rv.w + xv.w + cn[3] + gv[3]);
                }
            }
        }
    }
}

// ---------------------------------------------------------------------------
// 1x1 conv (MFMA) over concat([c,m]) fp32-cl -> h = o * tanh(conv + bias).
// B-frags read from global and split in-register; A-frags prepped split-f16.
// grid (16 px-chunks of 256, B); block = 4 waves, wave = M64 x N64.
// NOTE round-3/4 bug: grid.x was 64 -> blocks x>=16 wrote px in [4096,16384),
// scribbling 3 slabs past the output (c0/m0/c1 resp. hs[t+1]). Must be 16.
// ---------------------------------------------------------------------------
__global__ __launch_bounds__(256) void conv1x1m(
    const float* __restrict__ cten, const float* __restrict__ mten,
    const float* __restrict__ oten,
    const _Float16* __restrict__ W, const float* __restrict__ bias,
    float* houtp)
{
    const int tid = threadIdx.x;
    const int lane = tid & 63, wv = tid >> 6, tl = lane & 15, quad = lane >> 4;
    const int b = blockIdx.y;
    const int px0 = blockIdx.x * 256 + wv * 64;
    const long bb = (long)b * HWN * 64;

    floatx4 acc[4][4];
#pragma unroll
    for (int f = 0; f < 4; ++f)
#pragma unroll
        for (int g = 0; g < 4; ++g) acc[f][g] = (floatx4){0.f, 0.f, 0.f, 0.f};

#pragma unroll
    for (int c = 0; c < 4; ++c) {
        const float* src = (c < 2) ? cten : mten;
        const int ch0 = (c & 1) * 32 + quad * 8;
        f16x8 ah[4], al[4], bh[4], bl[4];
#pragma unroll
        for (int f = 0; f < 4; ++f) {
            const long wo = (long)(c * 4 + f) * 512 + lane * 8;
            ah[f] = *(const f16x8*)(W + wo);
            al[f] = *(const f16x8*)(W + 8192 + wo);
        }
#pragma unroll
        for (int g = 0; g < 4; ++g) {
            const long off = bb + (long)(px0 + g * 16 + tl) * 64 + ch0;
            float4 p0 = *(const float4*)(src + off);
            float4 p1 = *(const float4*)(src + off + 4);
            float vv[8] = {p0.x, p0.y, p0.z, p0.w, p1.x, p1.y, p1.z, p1.w};
            split8(vv, &bh[g], &bl[g]);
        }
#pragma unroll
        for (int f = 0; f < 4; ++f)
#pragma unroll
            for (int g = 0; g < 4; ++g) {
                acc[f][g] = __builtin_amdgcn_mfma_f32_16x16x32_f16(ah[f], bh[g], acc[f][g], 0, 0, 0);
                acc[f][g] = __builtin_amdgcn_mfma_f32_16x16x32_f16(ah[f], bl[g], acc[f][g], 0, 0, 0);
                acc[f][g] = __builtin_amdgcn_mfma_f32_16x16x32_f16(al[f], bh[g], acc[f][g], 0, 0, 0);
            }
    }

#pragma unroll
    for (int f = 0; f < 4; ++f) {
        const int co = f * 16 + quad * 4;
#pragma unroll
        for (int g = 0; g < 4; ++g) {
            const long off = bb + (long)(px0 + g * 16 + tl) * 64 + co;
            float4 ov = *(const float4*)(oten + off);
            float4 hv;
            hv.x = ov.x * tanhf(acc[f][g][0] + bias[co + 0]);
            hv.y = ov.y * tanhf(acc[f][g][1] + bias[co + 1]);
            hv.z = ov.z * tanhf(acc[f][g][2] + bias[co + 2]);
            hv.w = ov.w * tanhf(acc[f][g][3] + bias[co + 3]);
            *(float4*)(houtp + off) = hv;
        }
    }
}

// ---------------------------------------------------------------------------
// Gates: r,z,o,xr,xz + rc, xm — fp32 channels-last, 4 ch per thread.
// ---------------------------------------------------------------------------
__global__ __launch_bounds__(256) void gates_cl(
    const float* __restrict__ A, const float* __restrict__ Bm,
    const float* __restrict__ h, const float* __restrict__ m,
    const float* __restrict__ c,
    const float* __restrict__ td_h, const float* __restrict__ td_m,
    const float* __restrict__ tg,
    float* r, float* xr, float* z, float* xz,
    float* o, float* rc, float* xm)
{
    const int i  = blockIdx.x * 256 + threadIdx.x;     // 262144 total
    const int ch = (i & 15) * 4;
    const long px = (i >> 4) & 4095;
    const int b  = i >> 16;
    const long b64  = ((long)b * HWN + px) * 64 + ch;
    const long b192 = ((long)b * HWN + px) * 192 + ch;
    const long b128 = ((long)b * HWN + px) * 128 + ch;

    float4 Ar = *(const float4*)(A + b192);
    float4 Az = *(const float4*)(A + b192 + 64);
    float4 Ao = *(const float4*)(A + b192 + 128);
    float4 Br = *(const float4*)(Bm + b128);
    float4 Bz = *(const float4*)(Bm + b128 + 64);
    float4 hv = *(const float4*)(h + b64);
    float4 mv = *(const float4*)(m + b64);
    float4 cv = *(const float4*)(c + b64);

    float rv[4], zv[4], ov[4], xrv[4], xzv[4], rcv[4], xmv[4];
    const float* Arp = (const float*)&Ar; const float* Azp = (const float*)&Az;
    const float* Aop = (const float*)&Ao; const float* Brp = (const float*)&Br;
    const float* Bzp = (const float*)&Bz; const float* hp = (const float*)&hv;
    const float* mp = (const float*)&mv;  const float* cp = (const float*)&cv;
#pragma unroll
    for (int j = 0; j < 4; ++j) {
        const float g  = sigmoidf_(tg[ch + j]);
        const float dh = expf(-td_h[ch + j]);
        const float dm = expf(-td_m[ch + j]);
        rv[j]  = sigmoidf_(Arp[j] * g + hp[j] * dh);
        zv[j]  = sigmoidf_(Azp[j] * g + hp[j] * dh);
        ov[j]  = sigmoidf_(Aop[j]);
        xrv[j] = sigmoidf_(Brp[j] * g + mp[j] * dm);
        xzv[j] = sigmoidf_(Bzp[j] * g + mp[j] * dm);
        rcv[j] = rv[j] * cp[j];
        xmv[j] = xrv[j] * mp[j];
    }
    *(float4*)(r  + b64) = *(float4*)rv;
    *(float4*)(xr + b64) = *(float4*)xrv;
    *(float4*)(z  + b64) = *(float4*)zv;
    *(float4*)(xz + b64) = *(float4*)xzv;
    *(float4*)(o  + b64) = *(float4*)ov;
    *(float4*)(rc + b64) = *(float4*)rcv;
    *(float4*)(xm + b64) = *(float4*)xmv;
}

// ---------------------------------------------------------------------------
// logits split-K: grid (b, 16 K-chunks of 256 px); partial C[64][64] each.
// ---------------------------------------------------------------------------
__global__ __launch_bounds__(256) void logits_part(
    const float* __restrict__ q, const float* __restrict__ k, float* __restrict__ part)
{
    __shared__ float qs[64][66], ks[64][66];
    const int tid = threadIdx.x;
    const int b = blockIdx.x, kc = blockIdx.y;
    const int cqq = tid >> 4, ckq = tid & 15;
    float pacc[4][4];
#pragma unroll
    for (int u = 0; u < 4; ++u)
#pragma unroll
        for (int v = 0; v < 4; ++v) pacc[u][v] = 0.f;

    for (int sub = 0; sub < 4; ++sub) {
        const int px0 = kc * 256 + sub * 64;
        __syncthreads();
#pragma unroll
        for (int rr = 0; rr < 16; ++rr) {
            const int idx = rr * 256 + tid;
            const int chh = idx >> 6, pxo = idx & 63;
            qs[chh][pxo] = q[((long)b * 64 + chh) * HWN + px0 + pxo];
            ks[chh][pxo] = k[((long)b * 64 + chh) * HWN + px0 + pxo];
        }
        __syncthreads();
        for (int p = 0; p < 64; ++p) {
            float qv[4], kv[4];
#pragma unroll
            for (int u = 0; u < 4; ++u) { qv[u] = qs[cqq + 16 * u][p]; kv[u] = ks[ckq + 16 * u][p]; }
#pragma unroll
            for (int u = 0; u < 4; ++u)
#pragma unroll
                for (int v = 0; v < 4; ++v) pacc[u][v] = fmaf(qv[u], kv[v], pacc[u][v]);
        }
    }
#pragma unroll
    for (int u = 0; u < 4; ++u)
#pragma unroll
        for (int v = 0; v < 4; ++v)
            part[(((long)b * 16 + kc) * 64 + cqq + 16 * u) * 64 + ckq + 16 * v] = pacc[u][v];
}

// reduce 16 partials + softmax; one wave per (b,cq) row
__global__ void reduce_softmax(const float* __restrict__ part, float* __restrict__ attn)
{
    const int row = blockIdx.x;            // b*64 + cq
    const int b = row >> 6, cq = row & 63;
    const int lane = threadIdx.x;
    float s = 0.f;
#pragma unroll
    for (int kc = 0; kc < 16; ++kc)
        s += part[(((long)b * 16 + kc) * 64 + cq) * 64 + lane];
    float v = s * (1.f / 64.f);
    float mx = v;
    for (int off = 32; off; off >>= 1) mx = fmaxf(mx, __shfl_xor(mx, off));
    float e = expf(v - mx);
    float sum = e;
    for (int off = 32; off; off >>= 1) sum += __shfl_xor(sum, off);
    attn[row * 64 + lane] = e / sum;
}

// out[b,t,c,n] = sum_d attn[b,c,d] * v[t,b,n,d]   (v fp32 channels-last)
__global__ __launch_bounds__(256) void out_cl(
    const float* __restrict__ attn, const float* __restrict__ hs,
    float* __restrict__ outp)
{
    __shared__ __align__(16) float att_t[64][8];
    const int bt = blockIdx.x;
    const int b = bt >> 3, t = bt & 7;
    const int c0 = blockIdx.z * 8;
    const int tid = threadIdx.x;
    for (int i = tid; i < 512; i += 256) {
        int d = i >> 3, j = i & 7;
        att_t[d][j] = attn[(b * 64 + c0 + j) * 64 + d];
    }
    __syncthreads();

    const long px = blockIdx.y * 256 + tid;
    const long SLOT = (long)Bn * HWN * 64;
    const float* vb = hs + (long)t * SLOT + ((long)b * HWN + px) * 64;

    float acc[8];
#pragma unroll
    for (int j = 0; j < 8; ++j) acc[j] = 0.f;
#pragma unroll 4
    for (int dg = 0; dg < 16; ++dg) {
        float4 v4 = *(const float4*)(vb + dg * 4);
        const float* vp = (const float*)&v4;
#pragma unroll
        for (int j4 = 0; j4 < 4; ++j4) {
            const float vv = vp[j4];
            const float4 a0 = *(const float4*)&att_t[dg * 4 + j4][0];
            const float4 a1 = *(const float4*)&att_t[dg * 4 + j4][4];
            acc[0] = fmaf(vv, a0.x, acc[0]); acc[1] = fmaf(vv, a0.y, acc[1]);
            acc[2] = fmaf(vv, a0.z, acc[2]); acc[3] = fmaf(vv, a0.w, acc[3]);
            acc[4] = fmaf(vv, a1.x, acc[4]); acc[5] = fmaf(vv, a1.y, acc[5]);
            acc[6] = fmaf(vv, a1.z, acc[6]); acc[7] = fmaf(vv, a1.w, acc[7]);
        }
    }
    const long ob = ((long)(b * 8 + t) * 64 + c0) * HWN + px;
#pragma unroll
    for (int j = 0; j < 8; ++j) outp[ob + (long)j * HWN] = acc[j];
}

// ---------------------------------------------------------------------------
extern "C" void kernel_launch(void* const* d_in, const int* in_sizes, int n_in,
                              void* d_out, int out_size, void* d_ws, size_t ws_size,
                              hipStream_t stream)
{
    const float* x = (const float*)d_in[0];
    const float* w_rzo[2] = {(const float*)d_in[1],  (const float*)d_in[12]};
    const float* b_rzo[2] = {(const float*)d_in[2],  (const float*)d_in[13]};
    const float* w_rz[2]  = {(const float*)d_in[3],  (const float*)d_in[14]};
    const float* b_rz[2]  = {(const float*)d_in[4],  (const float*)d_in[15]};
    const float* w_h[2]   = {(const float*)d_in[5],  (const float*)d_in[16]};
    const float* b_h[2]   = {(const float*)d_in[6],  (const float*)d_in[17]};
    const float* w_o[2]   = {(const float*)d_in[7],  (const float*)d_in[18]};
    const float* b_o[2]   = {(const float*)d_in[8],  (const float*)d_in[19]};
    const float* td_h[2]  = {(const float*)d_in[9],  (const float*)d_in[20]};
    const float* td_m[2]  = {(const float*)d_in[10], (const float*)d_in[21]};
    const float* tg[2]    = {(const float*)d_in[11], (const float*)d_in[22]};

    // ---- workspace layout (fp32 channels-last activations) ----
    const size_t S64 = (size_t)Bn * HWN * 64;          // 1M floats = 4 MiB
    float* P = (float*)d_ws;
    float* h0    = P; P += S64;
    float* c0    = P; P += S64;
    float* m0    = P; P += S64;
    float* c1    = P; P += S64;
    float* m1    = P; P += S64;
    float* zslab = P; P += S64;                        // zeros; h1prev @ t=0
    float* A_cl  = P; P += (size_t)Bn * HWN * 192;     // 12 MiB
    float* B_cl  = P; P += (size_t)Bn * HWN * 128;     // 8 MiB
    float* rb    = P; P += S64;
    float* xrb   = P; P += S64;
    float* zb    = P; P += S64;
    float* xzb   = P; P += S64;
    float* ogb   = P; P += S64;
    float* rcb   = P; P += S64;
    float* xmb   = P; P += S64;
    float* hs    = P; P += (size_t)Tn * S64;           // 32 MiB
    float* x_cl  = P; P += (size_t)Tn * Bn * HWN * 16; // 8 MiB
    _Float16* wA0 = (_Float16*)P;
    _Float16* wB0 = wA0 + 331776;
    _Float16* wH0 = wB0 + 221184;
    _Float16* wA1 = wH0 + 110592;
    _Float16* wB1 = wA1 + 442368;
    _Float16* wH1 = wB1 + 294912;
    _Float16* wO0 = wH1 + 147456;
    _Float16* wO1 = wO0 + 16384;
    // q/k/partials/attn overlay A_cl (dead after last gates; logits run after)
    float* qbuf  = A_cl;
    float* kbuf  = qbuf + S64;                          // 4 MiB
    float* partb = kbuf + S64;                          // 1 MiB
    float* attnb = partb + (size_t)Bn * 16 * 64 * 64;   // 64 KiB

    hipMemsetAsync(h0, 0, 6 * S64 * sizeof(float), stream);

    prep_x_kernel<<<512, 256, 0, stream>>>(x, x_cl);
    prep_w_kernel<<<128, 256, 0, stream>>>(w_rzo[0], wA0, 80, 192, 3, 9);
    prep_w_kernel<<<128, 256, 0, stream>>>(w_rz[0],  wB0, 80, 128, 3, 9);
    prep_w_kernel<<<128, 256, 0, stream>>>(w_h[0],   wH0, 80,  64, 3, 9);
    prep_w_kernel<<<128, 256, 0, stream>>>(w_rzo[1], wA1, 128, 192, 4, 9);
    prep_w_kernel<<<128, 256, 0, stream>>>(w_rz[1],  wB1, 128, 128, 4, 9);
    prep_w_kernel<<<128, 256, 0, stream>>>(w_h[1],   wH1, 128, 64, 4, 9);
    prep_w_kernel<<<64, 256, 0, stream>>>(w_o[0], wO0, 128, 64, 4, 1);
    prep_w_kernel<<<64, 256, 0, stream>>>(w_o[1], wO1, 128, 64, 4, 1);

    for (int t = 0; t < Tn; ++t) {
        const float* xt = x_cl + (size_t)t * Bn * HWN * 16;
        const float* h1prev = (t == 0) ? zslab : (hs + (size_t)(t - 1) * S64);
        float* h1out = hs + (size_t)t * S64;

        // ---------- layer 0: inp=x_t, h=h0, c=c0, m_in=m1 -> m_out=m0 ----------
        conv3m<0, 4><<<dim3(16, 5, 4), 256, 0, stream>>>(
            xt, 16, h0, m1, 80, 3,
            wA0, b_rzo[0], A_cl, 192, 12,
            wB0, b_rz[0],  B_cl, 128, 8, 3,
            nullptr, nullptr, nullptr, nullptr, nullptr, nullptr, nullptr, nullptr, 0);
        gates_cl<<<1024, 256, 0, stream>>>(A_cl, B_cl, h0, m1, c0,
            td_h[0], td_m[0], tg[0], rb, xrb, zb, xzb, ogb, rcb, xmb);
        conv3m<1, 2><<<dim3(16, 2, 8), 256, 0, stream>>>(
            xt, 16, rcb, xmb, 80, 3,
            wH0, b_h[0], c0, 64, 4,
            wH0, b_h[0], m0, 64, 4, 0,
            zb, xzb, c0, m1, rb, xrb, qbuf, kbuf, 0);
        conv1x1m<<<dim3(16, 4), 256, 0, stream>>>(c0, m0, ogb, wO0, b_o[0], h0);

        // ---------- layer 1: inp=h0, h=hs[t-1], c=c1, m_in=m0 -> m_out=m1 -------
        conv3m<0, 4><<<dim3(16, 5, 4), 256, 0, stream>>>(
            h0, 64, h1prev, m0, 128, 4,
            wA1, b_rzo[1], A_cl, 192, 12,
            wB1, b_rz[1],  B_cl, 128, 8, 3,
            nullptr, nullptr, nullptr, nullptr, nullptr, nullptr, nullptr, nullptr, 0);
        gates_cl<<<1024, 256, 0, stream>>>(A_cl, B_cl, h1prev, m0, c1,
            td_h[1], td_m[1], tg[1], rb, xrb, zb, xzb, ogb, rcb, xmb);
        conv3m<1, 2><<<dim3(16, 2, 8), 256, 0, stream>>>(
            h0, 64, rcb, xmb, 128, 4,
            wH1, b_h[1], c1, 64, 4,
            wH1, b_h[1], m1, 64, 4, 0,
            zb, xzb, c1, m0, rb, xrb, qbuf, kbuf, (t == Tn - 1) ? 1 : 0);
        conv1x1m<<<dim3(16, 4), 256, 0, stream>>>(c1, m1, ogb, wO1, b_o[1], h1out);
    }

    // ---------- attention ----------
    logits_part<<<dim3(4, 16), 256, 0, stream>>>(qbuf, kbuf, partb);
    reduce_softmax<<<256, 64, 0, stream>>>(partb, attnb);
    out_cl<<<dim3(32, 16, 8), 256, 0, stream>>>(attnb, hs, (float*)d_out);
}

// Round 6
// 1468.120 us; speedup vs baseline: 9.2989x; 1.1573x over previous
//
#include <hip/hip_runtime.h>
#include <math.h>

#define HWN 4096
#define Bn 4
#define Tn 8

typedef __attribute__((ext_vector_type(8))) _Float16 f16x8;
typedef __attribute__((ext_vector_type(4))) float floatx4;

__device__ __forceinline__ float sigmoidf_(float v) { return 1.f / (1.f + expf(-v)); }

// split 8 fp32 -> f16 hi/lo vectors (value = hi + lo, ~22-bit effective)
__device__ __forceinline__ void split8(const float* vv, f16x8* hi, f16x8* lo) {
#pragma unroll
    for (int j = 0; j < 8; ++j) {
        _Float16 h = (_Float16)vv[j];
        (*hi)[j] = h;
        (*lo)[j] = (_Float16)(vv[j] - (float)h);
    }
}

// ---------------------------------------------------------------------------
// Weight prep: fp32 [Cout][Ctot][KK] -> A-fragment-swizzled split-f16:
// [plane][kk][chunk][cog][lane][j]; lane frag = 8 contiguous f16 (dwordx4).
// A-frag (16x16x32): A[m=lane&15][k=(lane>>4)*8+j].
// ---------------------------------------------------------------------------
__global__ __launch_bounds__(256) void prep_w_kernel(
    const float* __restrict__ W, _Float16* __restrict__ dst,
    int Ctot, int Cout, int nch, int KK)
{
    const int ncog = Cout >> 4;
    const long total = (long)KK * nch * ncog * 512;
    for (long i = (long)blockIdx.x * 256 + threadIdx.x; i < total;
         i += (long)gridDim.x * 256) {
        int j    = (int)(i & 7);
        int lane = (int)((i >> 3) & 63);
        long r   = i >> 9;
        int f = (int)(r % ncog); r /= ncog;
        int c = (int)(r % nch);  r /= nch;
        int kk = (int)r;
        int co = f * 16 + (lane & 15);
        int ci = c * 32 + (lane >> 4) * 8 + j;
        float v = (ci < Ctot) ? W[((long)co * Ctot + ci) * KK + kk] : 0.f;
        _Float16 hi = (_Float16)v;
        dst[i]         = hi;
        dst[total + i] = (_Float16)(v - (float)hi);
    }
}

// x fp32 [b][t][16][4096] -> x_cl fp32 [t][b][px][16]
__global__ __launch_bounds__(256) void prep_x_kernel(
    const float* __restrict__ x, float* __restrict__ xcl)
{
    const int i = blockIdx.x * 256 + threadIdx.x;     // 131072 total
    const int px = i & 4095;
    const int t  = (i >> 12) & 7;
    const int b  = i >> 15;
    float* d = xcl + (((long)t * Bn + b) * HWN + px) * 16;
#pragma unroll
    for (int ch = 0; ch < 16; ++ch)
        d[ch] = x[((long)(b * 8 + t) * 16 + ch) * HWN + px];
}

// ---------------------------------------------------------------------------
// MFMA implicit-GEMM 3x3 SAME conv. fp32 channels-last activations; hi/lo
// f16 split done while writing LDS. Latency-pipelined:
//  - next chunk's staging data prefetched into registers during MFMAs
//  - weight fragments double-buffered across kk (prefetch kk+1 during kk)
// EPI=0: plain conv, merged A/B dispatch (which = blockIdx.y >= nA).
// EPI=1: H-conv: tanh + fused state update (+ q/k on last cell);
//        which = blockIdx.z>>2 selects {rc,z,c}->c_new vs {xm,xz,m}->m_new.
// Block 256 thr = 4 waves; tile M = NF*16 couts x N = 256 px (16x16 spatial).
// LDS tile [18][18][plane][40] (halo, ci-contiguous for ds_read_b128).
// ---------------------------------------------------------------------------
template<int EPI, int NF>
__global__ __launch_bounds__(256) void conv3m(
    const float* __restrict__ in1, int C1,
    const float* __restrict__ in2a, const float* __restrict__ in2b,
    int Ctot, int nch,
    const _Float16* __restrict__ wA, const float* __restrict__ biasA,
    float* outA, int CoutA, int ncogA,
    const _Float16* __restrict__ wB, const float* __restrict__ biasB,
    float* outB, int CoutB, int ncogB, int nA,
    const float* zA, const float* zB,
    const float* sA, const float* sB,
    const float* rten, const float* xrten,
    float* qout, float* kout, int last)
{
    __shared__ __align__(16) _Float16 ldsB[18][18][2][40];

    const int tid = threadIdx.x;
    const int ty0 = (blockIdx.x >> 2) * 16;
    const int tx0 = (blockIdx.x & 3) * 16;
    const int b   = blockIdx.z & 3;
    const int which = (EPI == 1) ? (int)(blockIdx.z >> 2)
                                 : (blockIdx.y >= (unsigned)nA ? 1 : 0);

    const float*    in2  = which ? in2b : in2a;
    const _Float16* Wf   = which ? wB : wA;
    const float*    bias = which ? biasB : biasA;
    float*          outp = which ? outB : outA;
    const int Cout = which ? CoutB : CoutA;
    const int ncog = which ? ncogB : ncogA;
    const int cog0 = (EPI == 1) ? blockIdx.y * NF
                   : (which ? (blockIdx.y - nA) * NF : blockIdx.y * NF);
    const int co0  = cog0 * 16;

    const int lane = tid & 63, wv = tid >> 6, tl = lane & 15, quad = lane >> 4;
    const int C2 = Ctot - C1;
    const long wplane = (long)9 * nch * ncog * 512;
    const float* in1b  = in1 + (long)b * HWN * C1;
    const float* in2bb = in2 + (long)b * HWN * C2;

    floatx4 acc[NF][4];
#pragma unroll
    for (int f = 0; f < NF; ++f)
#pragma unroll
        for (int g = 0; g < 4; ++g) acc[f][g] = (floatx4){0.f, 0.f, 0.f, 0.f};

    // staging prefetch registers (next chunk's 8-ch groups)
    float4 pa[6], pb[6];
    auto prefetch = [&](int c) {
        const int c0 = c * 32;
#pragma unroll
        for (int s = 0; s < 6; ++s) {
            const int i = tid + s * 256;
            float4 va = {0.f, 0.f, 0.f, 0.f}, vb = {0.f, 0.f, 0.f, 0.f};
            if (i < 1296) {
                const int pxh = i >> 2, cig = i & 3;
                const int yh = pxh / 18, xh = pxh - yh * 18;
                const int y = ty0 + yh - 1, x = tx0 + xh - 1;
                const int ch = c0 + cig * 8;
                if (ch < Ctot && (unsigned)y < 64u && (unsigned)x < 64u) {
                    const float* src; long off;
                    if (ch < C1) { src = in1b;  off = (long)(y * 64 + x) * C1 + ch; }
                    else         { src = in2bb; off = (long)(y * 64 + x) * C2 + ch - C1; }
                    va = *(const float4*)(src + off);
                    vb = *(const float4*)(src + off + 4);
                }
            }
            pa[s] = va; pb[s] = vb;
        }
    };

    prefetch(0);

    for (int c = 0; c < nch; ++c) {
        __syncthreads();                     // protect LDS from prior readers
        // store prefetched chunk to LDS (split fp32 -> f16 hi/lo)
#pragma unroll
        for (int s = 0; s < 6; ++s) {
            const int i = tid + s * 256;
            if (i < 1296) {
                const int pxh = i >> 2, cig = i & 3;
                const int yh = pxh / 18, xh = pxh - yh * 18;
                float vv[8] = {pa[s].x, pa[s].y, pa[s].z, pa[s].w,
                               pb[s].x, pb[s].y, pb[s].z, pb[s].w};
                f16x8 vh, vl;
                split8(vv, &vh, &vl);
                *(f16x8*)&ldsB[yh][xh][0][cig * 8] = vh;
                *(f16x8*)&ldsB[yh][xh][1][cig * 8] = vl;
            }
        }
        __syncthreads();
        if (c + 1 < nch) prefetch(c + 1);   // overlap next staging with MFMAs

        // weight double-buffer across kk
        f16x8 wh[2][NF], wl[2][NF];
        {
            const long wo0 = ((long)(0 * nch + c) * ncog + cog0) * 512 + lane * 8;
#pragma unroll
            for (int f = 0; f < NF; ++f) {
                wh[0][f] = *(const f16x8*)(Wf + wo0 + (long)f * 512);
                wl[0][f] = *(const f16x8*)(Wf + wplane + wo0 + (long)f * 512);
            }
        }
#pragma unroll
        for (int kk = 0; kk < 9; ++kk) {
            const int cur = kk & 1, nxt = cur ^ 1;
            if (kk < 8) {
                const long wo = ((long)((kk + 1) * nch + c) * ncog + cog0) * 512 + lane * 8;
#pragma unroll
                for (int f = 0; f < NF; ++f) {
                    wh[nxt][f] = *(const f16x8*)(Wf + wo + (long)f * 512);
                    wl[nxt][f] = *(const f16x8*)(Wf + wplane + wo + (long)f * 512);
                }
            }
            const int ky = kk / 3, kx = kk - ky * 3;
            f16x8 bh[4], bl[4];
#pragma unroll
            for (int g = 0; g < 4; ++g) {
                const _Float16* pB = &ldsB[wv * 4 + g + ky][tl + kx][0][quad * 8];
                bh[g] = *(const f16x8*)pB;
                bl[g] = *(const f16x8*)(pB + 40);
            }
#pragma unroll
            for (int f = 0; f < NF; ++f)
#pragma unroll
                for (int g = 0; g < 4; ++g) {
                    acc[f][g] = __builtin_amdgcn_mfma_f32_16x16x32_f16(wh[cur][f], bh[g], acc[f][g], 0, 0, 0);
                    acc[f][g] = __builtin_amdgcn_mfma_f32_16x16x32_f16(wh[cur][f], bl[g], acc[f][g], 0, 0, 0);
                    acc[f][g] = __builtin_amdgcn_mfma_f32_16x16x32_f16(wl[cur][f], bh[g], acc[f][g], 0, 0, 0);
                }
        }
    }

    // epilogue: C/D layout col(px)=lane&15, row(co)=quad*4+reg
    if (EPI == 0) {
        const long obb = (long)b * HWN * Cout;
#pragma unroll
        for (int f = 0; f < NF; ++f) {
            const int co = co0 + f * 16 + quad * 4;
#pragma unroll
            for (int g = 0; g < 4; ++g) {
                const long px = (long)(ty0 + wv * 4 + g) * 64 + tx0 + tl;
                float4 v;
                v.x = acc[f][g][0] + bias[co + 0];
                v.y = acc[f][g][1] + bias[co + 1];
                v.z = acc[f][g][2] + bias[co + 2];
                v.w = acc[f][g][3] + bias[co + 3];
                *(float4*)(outp + obb + px * Cout + co) = v;
            }
        }
    } else {
        const float* zt = which ? zB : zA;
        const float* st = which ? sB : sA;
        float* qk = which ? kout : qout;
#pragma unroll
        for (int f = 0; f < NF; ++f) {
            const int co = co0 + f * 16 + quad * 4;
#pragma unroll
            for (int g = 0; g < 4; ++g) {
                const long px = (long)(ty0 + wv * 4 + g) * 64 + tx0 + tl;
                const long off = (long)b * HWN * 64 + px * 64 + co;
                float4 zv = *(const float4*)(zt + off);
                float4 sv = *(const float4*)(st + off);
                float gv[4], cn[4];
                gv[0] = tanhf(acc[f][g][0] + bias[co + 0]);
                gv[1] = tanhf(acc[f][g][1] + bias[co + 1]);
                gv[2] = tanhf(acc[f][g][2] + bias[co + 2]);
                gv[3] = tanhf(acc[f][g][3] + bias[co + 3]);
                cn[0] = zv.x * sv.x + (1.f - zv.x) * gv[0];
                cn[1] = zv.y * sv.y + (1.f - zv.y) * gv[1];
                cn[2] = zv.z * sv.z + (1.f - zv.z) * gv[2];
                cn[3] = zv.w * sv.w + (1.f - zv.w) * gv[3];
                *(float4*)(outp + off) = *(float4*)cn;
                if (last) {
                    float4 rv = *(const float4*)(rten + off);
                    float4 xv = *(const float4*)(xrten + off);
                    qk[((long)(b * 64) + co + 0) * HWN + px] = 0.25f * (rv.x + xv.x + cn[0] + gv[0]);
                    qk[((long)(b * 64) + co + 1) * HWN + px] = 0.25f * (rv.y + xv.y + cn[1] + gv[1]);
                    qk[((long)(b * 64) + co + 2) * HWN + px] = 0.25f * (rv.z + xv.z + cn[2] + gv[2]);
                    qk[((long)(b * 64) + co + 3) * HWN + px] = 0.25f * (rv.w + xv.w + cn[3] + gv[3]);
                }
            }
        }
    }
}

// ---------------------------------------------------------------------------
// 1x1 conv (MFMA) over concat([c,m]) fp32-cl -> h = o * tanh(conv + bias).
// grid (64, B) = 256 blocks; block = 4 waves; wave = 16 px x 64 co (all
// loads hoisted up front; no LDS, no barriers).
// ---------------------------------------------------------------------------
__global__ __launch_bounds__(256) void conv1x1m(
    const float* __restrict__ cten, const float* __restrict__ mten,
    const float* __restrict__ oten,
    const _Float16* __restrict__ W, const float* __restrict__ bias,
    float* houtp)
{
    const int tid = threadIdx.x;
    const int lane = tid & 63, wv = tid >> 6, tl = lane & 15, quad = lane >> 4;
    const int b = blockIdx.y;
    const int px = blockIdx.x * 64 + wv * 16 + tl;
    const long bb = (long)b * HWN * 64;

    // all weight fragments (4 chunks x 4 cout-frags, hi+lo)
    f16x8 wh[4][4], wl[4][4];
#pragma unroll
    for (int c = 0; c < 4; ++c)
#pragma unroll
        for (int f = 0; f < 4; ++f) {
            const long wo = (long)(c * 4 + f) * 512 + lane * 8;
            wh[c][f] = *(const f16x8*)(W + wo);
            wl[c][f] = *(const f16x8*)(W + 8192 + wo);
        }
    // all B fragments (4 chunks)
    f16x8 bh[4], bl[4];
#pragma unroll
    for (int c = 0; c < 4; ++c) {
        const float* src = (c < 2) ? cten : mten;
        const int ch0 = (c & 1) * 32 + quad * 8;
        const long off = bb + (long)px * 64 + ch0;
        float4 p0 = *(const float4*)(src + off);
        float4 p1 = *(const float4*)(src + off + 4);
        float vv[8] = {p0.x, p0.y, p0.z, p0.w, p1.x, p1.y, p1.z, p1.w};
        split8(vv, &bh[c], &bl[c]);
    }

    floatx4 acc[4];
#pragma unroll
    for (int f = 0; f < 4; ++f) acc[f] = (floatx4){0.f, 0.f, 0.f, 0.f};
#pragma unroll
    for (int c = 0; c < 4; ++c)
#pragma unroll
        for (int f = 0; f < 4; ++f) {
            acc[f] = __builtin_amdgcn_mfma_f32_16x16x32_f16(wh[c][f], bh[c], acc[f], 0, 0, 0);
            acc[f] = __builtin_amdgcn_mfma_f32_16x16x32_f16(wh[c][f], bl[c], acc[f], 0, 0, 0);
            acc[f] = __builtin_amdgcn_mfma_f32_16x16x32_f16(wl[c][f], bh[c], acc[f], 0, 0, 0);
        }

#pragma unroll
    for (int f = 0; f < 4; ++f) {
        const int co = f * 16 + quad * 4;
        const long off = bb + (long)px * 64 + co;
        float4 ov = *(const float4*)(oten + off);
        float4 hv;
        hv.x = ov.x * tanhf(acc[f][0] + bias[co + 0]);
        hv.y = ov.y * tanhf(acc[f][1] + bias[co + 1]);
        hv.z = ov.z * tanhf(acc[f][2] + bias[co + 2]);
        hv.w = ov.w * tanhf(acc[f][3] + bias[co + 3]);
        *(float4*)(houtp + off) = hv;
    }
}

// ---------------------------------------------------------------------------
// Gates: r,z,o,xr,xz + rc, xm — fp32 channels-last, 4 ch per thread.
// ---------------------------------------------------------------------------
__global__ __launch_bounds__(256) void gates_cl(
    const float* __restrict__ A, const float* __restrict__ Bm,
    const float* __restrict__ h, const float* __restrict__ m,
    const float* __restrict__ c,
    const float* __restrict__ td_h, const float* __restrict__ td_m,
    const float* __restrict__ tg,
    float* r, float* xr, float* z, float* xz,
    float* o, float* rc, float* xm)
{
    const int i  = blockIdx.x * 256 + threadIdx.x;     // 262144 total
    const int ch = (i & 15) * 4;
    const long px = (i >> 4) & 4095;
    const int b  = i >> 16;
    const long b64  = ((long)b * HWN + px) * 64 + ch;
    const long b192 = ((long)b * HWN + px) * 192 + ch;
    const long b128 = ((long)b * HWN + px) * 128 + ch;

    float4 Ar = *(const float4*)(A + b192);
    float4 Az = *(const float4*)(A + b192 + 64);
    float4 Ao = *(const float4*)(A + b192 + 128);
    float4 Br = *(const float4*)(Bm + b128);
    float4 Bz = *(const float4*)(Bm + b128 + 64);
    float4 hv = *(const float4*)(h + b64);
    float4 mv = *(const float4*)(m + b64);
    float4 cv = *(const float4*)(c + b64);

    float rv[4], zv[4], ov[4], xrv[4], xzv[4], rcv[4], xmv[4];
    const float* Arp = (const float*)&Ar; const float* Azp = (const float*)&Az;
    const float* Aop = (const float*)&Ao; const float* Brp = (const float*)&Br;
    const float* Bzp = (const float*)&Bz; const float* hp = (const float*)&hv;
    const float* mp = (const float*)&mv;  const float* cp = (const float*)&cv;
#pragma unroll
    for (int j = 0; j < 4; ++j) {
        const float g  = sigmoidf_(tg[ch + j]);
        const float dh = expf(-td_h[ch + j]);
        const float dm = expf(-td_m[ch + j]);
        rv[j]  = sigmoidf_(Arp[j] * g + hp[j] * dh);
        zv[j]  = sigmoidf_(Azp[j] * g + hp[j] * dh);
        ov[j]  = sigmoidf_(Aop[j]);
        xrv[j] = sigmoidf_(Brp[j] * g + mp[j] * dm);
        xzv[j] = sigmoidf_(Bzp[j] * g + mp[j] * dm);
        rcv[j] = rv[j] * cp[j];
        xmv[j] = xrv[j] * mp[j];
    }
    *(float4*)(r  + b64) = *(float4*)rv;
    *(float4*)(xr + b64) = *(float4*)xrv;
    *(float4*)(z  + b64) = *(float4*)zv;
    *(float4*)(xz + b64) = *(float4*)xzv;
    *(float4*)(o  + b64) = *(float4*)ov;
    *(float4*)(rc + b64) = *(float4*)rcv;
    *(float4*)(xm + b64) = *(float4*)xmv;
}

// ---------------------------------------------------------------------------
// logits split-K: grid (b, 16 K-chunks of 256 px); partial C[64][64] each.
// ---------------------------------------------------------------------------
__global__ __launch_bounds__(256) void logits_part(
    const float* __restrict__ q, const float* __restrict__ k, float* __restrict__ part)
{
    __shared__ float qs[64][66], ks[64][66];
    const int tid = threadIdx.x;
    const int b = blockIdx.x, kc = blockIdx.y;
    const int cqq = tid >> 4, ckq = tid & 15;
    float pacc[4][4];
#pragma unroll
    for (int u = 0; u < 4; ++u)
#pragma unroll
        for (int v = 0; v < 4; ++v) pacc[u][v] = 0.f;

    for (int sub = 0; sub < 4; ++sub) {
        const int px0 = kc * 256 + sub * 64;
        __syncthreads();
#pragma unroll
        for (int rr = 0; rr < 16; ++rr) {
            const int idx = rr * 256 + tid;
            const int chh = idx >> 6, pxo = idx & 63;
            qs[chh][pxo] = q[((long)b * 64 + chh) * HWN + px0 + pxo];
            ks[chh][pxo] = k[((long)b * 64 + chh) * HWN + px0 + pxo];
        }
        __syncthreads();
        for (int p = 0; p < 64; ++p) {
            float qv[4], kv[4];
#pragma unroll
            for (int u = 0; u < 4; ++u) { qv[u] = qs[cqq + 16 * u][p]; kv[u] = ks[ckq + 16 * u][p]; }
#pragma unroll
            for (int u = 0; u < 4; ++u)
#pragma unroll
                for (int v = 0; v < 4; ++v) pacc[u][v] = fmaf(qv[u], kv[v], pacc[u][v]);
        }
    }
#pragma unroll
    for (int u = 0; u < 4; ++u)
#pragma unroll
        for (int v = 0; v < 4; ++v)
            part[(((long)b * 16 + kc) * 64 + cqq + 16 * u) * 64 + ckq + 16 * v] = pacc[u][v];
}

// reduce 16 partials + softmax; one wave per (b,cq) row
__global__ void reduce_softmax(const float* __restrict__ part, float* __restrict__ attn)
{
    const int row = blockIdx.x;            // b*64 + cq
    const int b = row >> 6, cq = row & 63;
    const int lane = threadIdx.x;
    float s = 0.f;
#pragma unroll
    for (int kc = 0; kc < 16; ++kc)
        s += part[(((long)b * 16 + kc) * 64 + cq) * 64 + lane];
    float v = s * (1.f / 64.f);
    float mx = v;
    for (int off = 32; off; off >>= 1) mx = fmaxf(mx, __shfl_xor(mx, off));
    float e = expf(v - mx);
    float sum = e;
    for (int off = 32; off; off >>= 1) sum += __shfl_xor(sum, off);
    attn[row * 64 + lane] = e / sum;
}

// out[b,t,c,n] = sum_d attn[b,c,d] * v[t,b,n,d]   (v fp32 channels-last)
__global__ __launch_bounds__(256) void out_cl(
    const float* __restrict__ attn, const float* __restrict__ hs,
    float* __restrict__ outp)
{
    __shared__ __align__(16) float att_t[64][8];
    const int bt = blockIdx.x;
    const int b = bt >> 3, t = bt & 7;
    const int c0 = blockIdx.z * 8;
    const int tid = threadIdx.x;
    for (int i = tid; i < 512; i += 256) {
        int d = i >> 3, j = i & 7;
        att_t[d][j] = attn[(b * 64 + c0 + j) * 64 + d];
    }
    __syncthreads();

    const long px = blockIdx.y * 256 + tid;
    const long SLOT = (long)Bn * HWN * 64;
    const float* vb = hs + (long)t * SLOT + ((long)b * HWN + px) * 64;

    float acc[8];
#pragma unroll
    for (int j = 0; j < 8; ++j) acc[j] = 0.f;
#pragma unroll 4
    for (int dg = 0; dg < 16; ++dg) {
        float4 v4 = *(const float4*)(vb + dg * 4);
        const float* vp = (const float*)&v4;
#pragma unroll
        for (int j4 = 0; j4 < 4; ++j4) {
            const float vv = vp[j4];
            const float4 a0 = *(const float4*)&att_t[dg * 4 + j4][0];
            const float4 a1 = *(const float4*)&att_t[dg * 4 + j4][4];
            acc[0] = fmaf(vv, a0.x, acc[0]); acc[1] = fmaf(vv, a0.y, acc[1]);
            acc[2] = fmaf(vv, a0.z, acc[2]); acc[3] = fmaf(vv, a0.w, acc[3]);
            acc[4] = fmaf(vv, a1.x, acc[4]); acc[5] = fmaf(vv, a1.y, acc[5]);
            acc[6] = fmaf(vv, a1.z, acc[6]); acc[7] = fmaf(vv, a1.w, acc[7]);
        }
    }
    const long ob = ((long)(b * 8 + t) * 64 + c0) * HWN + px;
#pragma unroll
    for (int j = 0; j < 8; ++j) outp[ob + (long)j * HWN] = acc[j];
}

// ---------------------------------------------------------------------------
extern "C" void kernel_launch(void* const* d_in, const int* in_sizes, int n_in,
                              void* d_out, int out_size, void* d_ws, size_t ws_size,
                              hipStream_t stream)
{
    const float* x = (const float*)d_in[0];
    const float* w_rzo[2] = {(const float*)d_in[1],  (const float*)d_in[12]};
    const float* b_rzo[2] = {(const float*)d_in[2],  (const float*)d_in[13]};
    const float* w_rz[2]  = {(const float*)d_in[3],  (const float*)d_in[14]};
    const float* b_rz[2]  = {(const float*)d_in[4],  (const float*)d_in[15]};
    const float* w_h[2]   = {(const float*)d_in[5],  (const float*)d_in[16]};
    const float* b_h[2]   = {(const float*)d_in[6],  (const float*)d_in[17]};
    const float* w_o[2]   = {(const float*)d_in[7],  (const float*)d_in[18]};
    const float* b_o[2]   = {(const float*)d_in[8],  (const float*)d_in[19]};
    const float* td_h[2]  = {(const float*)d_in[9],  (const float*)d_in[20]};
    const float* td_m[2]  = {(const float*)d_in[10], (const float*)d_in[21]};
    const float* tg[2]    = {(const float*)d_in[11], (const float*)d_in[22]};

    // ---- workspace layout (fp32 channels-last activations) ----
    const size_t S64 = (size_t)Bn * HWN * 64;          // 1M floats = 4 MiB
    float* P = (float*)d_ws;
    float* h0    = P; P += S64;
    float* c0    = P; P += S64;
    float* m0    = P; P += S64;
    float* c1    = P; P += S64;
    float* m1    = P; P += S64;
    float* zslab = P; P += S64;                        // zeros; h1prev @ t=0
    float* A_cl  = P; P += (size_t)Bn * HWN * 192;     // 12 MiB
    float* B_cl  = P; P += (size_t)Bn * HWN * 128;     // 8 MiB
    float* rb    = P; P += S64;
    float* xrb   = P; P += S64;
    float* zb    = P; P += S64;
    float* xzb   = P; P += S64;
    float* ogb   = P; P += S64;
    float* rcb   = P; P += S64;
    float* xmb   = P; P += S64;
    float* hs    = P; P += (size_t)Tn * S64;           // 32 MiB
    float* x_cl  = P; P += (size_t)Tn * Bn * HWN * 16; // 8 MiB
    _Float16* wA0 = (_Float16*)P;
    _Float16* wB0 = wA0 + 331776;
    _Float16* wH0 = wB0 + 221184;
    _Float16* wA1 = wH0 + 110592;
    _Float16* wB1 = wA1 + 442368;
    _Float16* wH1 = wB1 + 294912;
    _Float16* wO0 = wH1 + 147456;
    _Float16* wO1 = wO0 + 16384;
    // q/k/partials/attn overlay A_cl (dead after last gates; logits run after)
    float* qbuf  = A_cl;
    float* kbuf  = qbuf + S64;                          // 4 MiB
    float* partb = kbuf + S64;                          // 1 MiB
    float* attnb = partb + (size_t)Bn * 16 * 64 * 64;   // 64 KiB

    hipMemsetAsync(h0, 0, 6 * S64 * sizeof(float), stream);

    prep_x_kernel<<<512, 256, 0, stream>>>(x, x_cl);
    prep_w_kernel<<<128, 256, 0, stream>>>(w_rzo[0], wA0, 80, 192, 3, 9);
    prep_w_kernel<<<128, 256, 0, stream>>>(w_rz[0],  wB0, 80, 128, 3, 9);
    prep_w_kernel<<<128, 256, 0, stream>>>(w_h[0],   wH0, 80,  64, 3, 9);
    prep_w_kernel<<<128, 256, 0, stream>>>(w_rzo[1], wA1, 128, 192, 4, 9);
    prep_w_kernel<<<128, 256, 0, stream>>>(w_rz[1],  wB1, 128, 128, 4, 9);
    prep_w_kernel<<<128, 256, 0, stream>>>(w_h[1],   wH1, 128, 64, 4, 9);
    prep_w_kernel<<<64, 256, 0, stream>>>(w_o[0], wO0, 128, 64, 4, 1);
    prep_w_kernel<<<64, 256, 0, stream>>>(w_o[1], wO1, 128, 64, 4, 1);

    for (int t = 0; t < Tn; ++t) {
        const float* xt = x_cl + (size_t)t * Bn * HWN * 16;
        const float* h1prev = (t == 0) ? zslab : (hs + (size_t)(t - 1) * S64);
        float* h1out = hs + (size_t)t * S64;

        // ---------- layer 0: inp=x_t, h=h0, c=c0, m_in=m1 -> m_out=m0 ----------
        conv3m<0, 2><<<dim3(16, 10, 4), 256, 0, stream>>>(
            xt, 16, h0, m1, 80, 3,
            wA0, b_rzo[0], A_cl, 192, 12,
            wB0, b_rz[0],  B_cl, 128, 8, 6,
            nullptr, nullptr, nullptr, nullptr, nullptr, nullptr, nullptr, nullptr, 0);
        gates_cl<<<1024, 256, 0, stream>>>(A_cl, B_cl, h0, m1, c0,
            td_h[0], td_m[0], tg[0], rb, xrb, zb, xzb, ogb, rcb, xmb);
        conv3m<1, 1><<<dim3(16, 4, 8), 256, 0, stream>>>(
            xt, 16, rcb, xmb, 80, 3,
            wH0, b_h[0], c0, 64, 4,
            wH0, b_h[0], m0, 64, 4, 0,
            zb, xzb, c0, m1, rb, xrb, qbuf, kbuf, 0);
        conv1x1m<<<dim3(64, 4), 256, 0, stream>>>(c0, m0, ogb, wO0, b_o[0], h0);

        // ---------- layer 1: inp=h0, h=hs[t-1], c=c1, m_in=m0 -> m_out=m1 -------
        conv3m<0, 2><<<dim3(16, 10, 4), 256, 0, stream>>>(
            h0, 64, h1prev, m0, 128, 4,
            wA1, b_rzo[1], A_cl, 192, 12,
            wB1, b_rz[1],  B_cl, 128, 8, 6,
            nullptr, nullptr, nullptr, nullptr, nullptr, nullptr, nullptr, nullptr, 0);
        gates_cl<<<1024, 256, 0, stream>>>(A_cl, B_cl, h1prev, m0, c1,
            td_h[1], td_m[1], tg[1], rb, xrb, zb, xzb, ogb, rcb, xmb);
        conv3m<1, 1><<<dim3(16, 4, 8), 256, 0, stream>>>(
            h0, 64, rcb, xmb, 128, 4,
            wH1, b_h[1], c1, 64, 4,
            wH1, b_h[1], m1, 64, 4, 0,
            zb, xzb, c1, m0, rb, xrb, qbuf, kbuf, (t == Tn - 1) ? 1 : 0);
        conv1x1m<<<dim3(64, 4), 256, 0, stream>>>(c1, m1, ogb, wO1, b_o[1], h1out);
    }

    // ---------- attention ----------
    logits_part<<<dim3(4, 16), 256, 0, stream>>>(qbuf, kbuf, partb);
    reduce_softmax<<<256, 64, 0, stream>>>(partb, attnb);
    out_cl<<<dim3(32, 16, 8), 256, 0, stream>>>(attnb, hs, (float*)d_out);
}